// Round 1
// baseline (281.541 us; speedup 1.0000x reference)
//
#include <hip/hip_runtime.h>
#include <hip/hip_bf16.h>
#include <math.h>

// Problem constants (from reference)
#define Dn 256     // feature dim
#define En 16      // hyperedges per node
#define Kn 3       // nodes per hyperedge
#define Hn 256     // hidden dim
#define Cn 40      // classes

// ---------------------------------------------------------------------------
// Stage 1: message passing. One wave (64 lanes) per node b.
// Each lane owns 4 consecutive feature dims (float4): 64*16B = 1KB = one X row.
// h_out[b] = X[nodes[b]] + sum_e sigmoid(waw*var_e + wab) * (f0*f1)
// ---------------------------------------------------------------------------
__global__ __launch_bounds__(256) void mp_kernel(
    const int* __restrict__ nodes, const int* __restrict__ structure,
    const float* __restrict__ X, const float* __restrict__ waw_p,
    const float* __restrict__ wab_p, float* __restrict__ h_out, int B)
{
    const int wave = threadIdx.x >> 6;
    const int lane = threadIdx.x & 63;
    const int b = blockIdx.x * 4 + wave;
    if (b >= B) return;

    const float waw = waw_p[0];
    const float wab = wab_p[0];
    const float4* __restrict__ Xv = reinterpret_cast<const float4*>(X);

    float4 neigh = make_float4(0.f, 0.f, 0.f, 0.f);
    const int* st = structure + (size_t)b * (En * Kn);

    #pragma unroll 1
    for (int e = 0; e < En; ++e) {
        const int i0 = st[e * 3 + 0];
        const int i1 = st[e * 3 + 1];
        const int i2 = st[e * 3 + 2];
        const float4 f0 = Xv[i0 * (Dn / 4) + lane];
        const float4 f1 = Xv[i1 * (Dn / 4) + lane];
        const float4 f2 = Xv[i2 * (Dn / 4) + lane];

        // per-lane partial of sum_d var_d   (var = E[x^2] - mean^2, ddof=0)
        float pv = 0.f;
        {
            float a, bb, c, m;
            a = f0.x; bb = f1.x; c = f2.x;
            m = (a + bb + c) * (1.f / 3.f);
            pv += (a * a + bb * bb + c * c) * (1.f / 3.f) - m * m;
            a = f0.y; bb = f1.y; c = f2.y;
            m = (a + bb + c) * (1.f / 3.f);
            pv += (a * a + bb * bb + c * c) * (1.f / 3.f) - m * m;
            a = f0.z; bb = f1.z; c = f2.z;
            m = (a + bb + c) * (1.f / 3.f);
            pv += (a * a + bb * bb + c * c) * (1.f / 3.f) - m * m;
            a = f0.w; bb = f1.w; c = f2.w;
            m = (a + bb + c) * (1.f / 3.f);
            pv += (a * a + bb * bb + c * c) * (1.f / 3.f) - m * m;
        }
        // wave-wide sum (64 lanes)
        #pragma unroll
        for (int off = 32; off; off >>= 1) pv += __shfl_xor(pv, off);
        const float var_mean = pv * (1.f / (float)Dn);
        const float att = 1.f / (1.f + expf(-(waw * var_mean + wab)));

        neigh.x += att * f0.x * f1.x;
        neigh.y += att * f0.y * f1.y;
        neigh.z += att * f0.z * f1.z;
        neigh.w += att * f0.w * f1.w;
    }

    const float4 s = Xv[nodes[b] * (Dn / 4) + lane];
    float4 h;
    h.x = s.x + neigh.x; h.y = s.y + neigh.y;
    h.z = s.z + neigh.z; h.w = s.w + neigh.w;
    reinterpret_cast<float4*>(h_out)[(size_t)b * (Dn / 4) + lane] = h;
}

// ---------------------------------------------------------------------------
// Stage 2: fused dual GEMM (fp32 vector — no fp32 MFMA on CDNA4).
//   enc2 = (1-beta)*relu(h @ lin_W^T + lin_b) + beta*(self @ skip_W^T)
// self rows are gathered on the fly: self[r] = X[nodes[r]].
// Tile 64x64, 256 threads, 4x4 per-thread microtile, BK=16.
// LDS holds K-transposed tiles padded to 68 so fragments are aligned b128.
// ---------------------------------------------------------------------------
#define BM 64
#define BN 64
#define BKs 16
#define LDT 68  // 64 + 4 pad: keeps float4 alignment, spreads banks

__global__ __launch_bounds__(256) void enc_gemm(
    const float* __restrict__ hA, const int* __restrict__ nodes,
    const float* __restrict__ X,
    const float* __restrict__ linW, const float* __restrict__ linb,
    const float* __restrict__ skipW, const float* __restrict__ beta_p,
    float* __restrict__ enc2, int M)
{
    __shared__ float Ats1[BKs][LDT];  // h tile, [k][row]
    __shared__ float Ats2[BKs][LDT];  // self tile, [k][row]
    __shared__ float Bts1[BKs][LDT];  // lin_W tile, [k][col]
    __shared__ float Bts2[BKs][LDT];  // skip_W tile, [k][col]

    const int tid = threadIdx.x;
    const int tx = tid & 15;    // col quad 0..15
    const int ty = tid >> 4;    // row quad 0..15
    const int row0 = blockIdx.x * BM;
    const int col0 = blockIdx.y * BN;

    const int lr = tid >> 2;    // 0..63 : tile row (A) / tile col (B)
    const int lc = tid & 3;     // 0..3  : k-quad

    const int arow = row0 + lr;
    const bool arow_ok = arow < M;
    const int self_row = arow_ok ? nodes[arow] : 0;

    float acc1[4][4] = {{0.f}}, acc2[4][4] = {{0.f}};

    for (int k0 = 0; k0 < Dn; k0 += BKs) {
        float4 a1v = make_float4(0.f, 0.f, 0.f, 0.f);
        float4 a2v = make_float4(0.f, 0.f, 0.f, 0.f);
        if (arow_ok) {
            a1v = *reinterpret_cast<const float4*>(hA + (size_t)arow * Dn + k0 + lc * 4);
            a2v = *reinterpret_cast<const float4*>(X + (size_t)self_row * Dn + k0 + lc * 4);
        }
        const float4 b1v = *reinterpret_cast<const float4*>(linW + (size_t)(col0 + lr) * Dn + k0 + lc * 4);
        const float4 b2v = *reinterpret_cast<const float4*>(skipW + (size_t)(col0 + lr) * Dn + k0 + lc * 4);

        __syncthreads();  // previous iteration finished reading LDS
        Ats1[lc * 4 + 0][lr] = a1v.x; Ats1[lc * 4 + 1][lr] = a1v.y;
        Ats1[lc * 4 + 2][lr] = a1v.z; Ats1[lc * 4 + 3][lr] = a1v.w;
        Ats2[lc * 4 + 0][lr] = a2v.x; Ats2[lc * 4 + 1][lr] = a2v.y;
        Ats2[lc * 4 + 2][lr] = a2v.z; Ats2[lc * 4 + 3][lr] = a2v.w;
        Bts1[lc * 4 + 0][lr] = b1v.x; Bts1[lc * 4 + 1][lr] = b1v.y;
        Bts1[lc * 4 + 2][lr] = b1v.z; Bts1[lc * 4 + 3][lr] = b1v.w;
        Bts2[lc * 4 + 0][lr] = b2v.x; Bts2[lc * 4 + 1][lr] = b2v.y;
        Bts2[lc * 4 + 2][lr] = b2v.z; Bts2[lc * 4 + 3][lr] = b2v.w;
        __syncthreads();

        #pragma unroll
        for (int kk = 0; kk < BKs; ++kk) {
            const float4 a1 = *reinterpret_cast<const float4*>(&Ats1[kk][ty * 4]);
            const float4 a2 = *reinterpret_cast<const float4*>(&Ats2[kk][ty * 4]);
            const float4 b1 = *reinterpret_cast<const float4*>(&Bts1[kk][tx * 4]);
            const float4 b2 = *reinterpret_cast<const float4*>(&Bts2[kk][tx * 4]);
            const float a1a[4] = {a1.x, a1.y, a1.z, a1.w};
            const float a2a[4] = {a2.x, a2.y, a2.z, a2.w};
            const float b1a[4] = {b1.x, b1.y, b1.z, b1.w};
            const float b2a[4] = {b2.x, b2.y, b2.z, b2.w};
            #pragma unroll
            for (int i = 0; i < 4; ++i)
                #pragma unroll
                for (int j = 0; j < 4; ++j) {
                    acc1[i][j] = fmaf(a1a[i], b1a[j], acc1[i][j]);
                    acc2[i][j] = fmaf(a2a[i], b2a[j], acc2[i][j]);
                }
        }
    }

    const float beta = beta_p[0];
    const float omb = 1.f - beta;
    #pragma unroll
    for (int i = 0; i < 4; ++i) {
        const int r = row0 + ty * 4 + i;
        if (r >= M) continue;
        #pragma unroll
        for (int j = 0; j < 4; ++j) {
            const int c = col0 + tx * 4 + j;
            float c1 = acc1[i][j] + linb[c];
            c1 = fmaxf(c1, 0.f);
            enc2[(size_t)r * Hn + c] = omb * c1 + beta * acc2[i][j];
        }
    }
}

// ---------------------------------------------------------------------------
// Stage 3: classifier + log_softmax. One wave per node b.
// ---------------------------------------------------------------------------
__global__ __launch_bounds__(256) void cls_kernel(
    const float* __restrict__ enc2, const float* __restrict__ clsW,
    const float* __restrict__ clsb, float* __restrict__ out, int B)
{
    const int wave = threadIdx.x >> 6;
    const int lane = threadIdx.x & 63;
    const int b = blockIdx.x * 4 + wave;
    if (b >= B) return;

    const float4 e = reinterpret_cast<const float4*>(enc2 + (size_t)b * Hn)[lane];

    float mylogit = -INFINITY;
    #pragma unroll 1
    for (int c = 0; c < Cn; ++c) {
        const float4 wv = reinterpret_cast<const float4*>(clsW + (size_t)c * Hn)[lane];
        float p = e.x * wv.x + e.y * wv.y + e.z * wv.z + e.w * wv.w;
        #pragma unroll
        for (int off = 32; off; off >>= 1) p += __shfl_xor(p, off);
        if (lane == c) mylogit = p;
    }
    if (lane < Cn) mylogit += clsb[lane];

    float mx = mylogit;
    #pragma unroll
    for (int off = 32; off; off >>= 1) mx = fmaxf(mx, __shfl_xor(mx, off));
    float ex = (lane < Cn) ? expf(mylogit - mx) : 0.f;
    float se = ex;
    #pragma unroll
    for (int off = 32; off; off >>= 1) se += __shfl_xor(se, off);
    const float lse = logf(se);

    if (lane < Cn) out[(size_t)b * Cn + lane] = mylogit - mx - lse;
}

// ---------------------------------------------------------------------------
extern "C" void kernel_launch(void* const* d_in, const int* in_sizes, int n_in,
                              void* d_out, int out_size, void* d_ws, size_t ws_size,
                              hipStream_t stream) {
    const int*   nodes     = (const int*)d_in[0];
    const int*   structure = (const int*)d_in[1];
    const float* X         = (const float*)d_in[2];
    const float* beta      = (const float*)d_in[3];
    const float* waw       = (const float*)d_in[4];
    const float* wab       = (const float*)d_in[5];
    const float* linW      = (const float*)d_in[6];
    const float* linb      = (const float*)d_in[7];
    const float* skipW     = (const float*)d_in[8];
    const float* clsW      = (const float*)d_in[9];
    const float* clsb      = (const float*)d_in[10];
    float* out = (float*)d_out;

    const int B = in_sizes[0];

    float* h    = (float*)d_ws;                       // [B, D]
    float* enc2 = h + (size_t)B * Dn;                 // [B, H]

    // Stage 1: message passing -> h
    mp_kernel<<<(B + 3) / 4, 256, 0, stream>>>(nodes, structure, X, waw, wab, h, B);

    // Stage 2: fused dual GEMM -> enc2
    dim3 g2((B + BM - 1) / BM, Hn / BN);
    enc_gemm<<<g2, 256, 0, stream>>>(h, nodes, X, linW, linb, skipW, beta, enc2, B);

    // Stage 3: classifier + log_softmax -> out
    cls_kernel<<<(B + 3) / 4, 256, 0, stream>>>(enc2, clsW, clsb, out, B);
}

// Round 2
// 278.682 us; speedup vs baseline: 1.0103x; 1.0103x over previous
//
#include <hip/hip_runtime.h>
#include <hip/hip_bf16.h>
#include <math.h>

// Problem constants (from reference)
#define Dn 256     // feature dim
#define En 16      // hyperedges per node
#define Kn 3       // nodes per hyperedge
#define Hn 256     // hidden dim
#define Cn 40      // classes

// ---------------------------------------------------------------------------
// Stage 1: message passing. One wave (64 lanes) per node b.
// Each lane owns 4 consecutive feature dims (float4): 64*16B = 1KB = one X row.
// h_out[b] = X[nodes[b]] + sum_e sigmoid(waw*var_e + wab) * (f0*f1)
//
// v2: edges processed in groups of 4 -> 12 float4 gathers in flight per wave,
// 4 interleaved shfl-butterfly reductions (pipelined latency), wave-uniform
// index loads via readfirstlane (s_load path).
// ---------------------------------------------------------------------------
__global__ __launch_bounds__(256) void mp_kernel(
    const int* __restrict__ nodes, const int* __restrict__ structure,
    const float* __restrict__ X, const float* __restrict__ waw_p,
    const float* __restrict__ wab_p, float* __restrict__ h_out, int B)
{
    const int wave = threadIdx.x >> 6;
    const int lane = threadIdx.x & 63;
    const int b = blockIdx.x * 4 + wave;
    if (b >= B) return;
    const int ub = __builtin_amdgcn_readfirstlane(b);  // wave-uniform

    const float waw = waw_p[0];
    const float wab = wab_p[0];
    const float4* __restrict__ Xv = reinterpret_cast<const float4*>(X);

    float4 neigh = make_float4(0.f, 0.f, 0.f, 0.f);
    const int* st = structure + (size_t)ub * (En * Kn);

    #pragma unroll 1
    for (int g = 0; g < En / 4; ++g) {
        // 12 wave-uniform indices (scalar loads)
        int idx[12];
        #pragma unroll
        for (int u = 0; u < 12; ++u) idx[u] = st[g * 12 + u];

        // 12 independent 1KB row gathers in flight
        float4 f0[4], f1[4], f2[4];
        #pragma unroll
        for (int u = 0; u < 4; ++u) {
            f0[u] = Xv[(size_t)idx[u * 3 + 0] * (Dn / 4) + lane];
            f1[u] = Xv[(size_t)idx[u * 3 + 1] * (Dn / 4) + lane];
            f2[u] = Xv[(size_t)idx[u * 3 + 2] * (Dn / 4) + lane];
        }

        // per-lane variance partials + product message; f's die here
        float pv[4];
        float4 msg[4];
        #pragma unroll
        for (int u = 0; u < 4; ++u) {
            float s = 0.f;
            {
                float a, bb, c, m;
                a = f0[u].x; bb = f1[u].x; c = f2[u].x;
                m = (a + bb + c) * (1.f / 3.f);
                s += (a * a + bb * bb + c * c) * (1.f / 3.f) - m * m;
                a = f0[u].y; bb = f1[u].y; c = f2[u].y;
                m = (a + bb + c) * (1.f / 3.f);
                s += (a * a + bb * bb + c * c) * (1.f / 3.f) - m * m;
                a = f0[u].z; bb = f1[u].z; c = f2[u].z;
                m = (a + bb + c) * (1.f / 3.f);
                s += (a * a + bb * bb + c * c) * (1.f / 3.f) - m * m;
                a = f0[u].w; bb = f1[u].w; c = f2[u].w;
                m = (a + bb + c) * (1.f / 3.f);
                s += (a * a + bb * bb + c * c) * (1.f / 3.f) - m * m;
            }
            pv[u] = s;
            msg[u].x = f0[u].x * f1[u].x;
            msg[u].y = f0[u].y * f1[u].y;
            msg[u].z = f0[u].z * f1[u].z;
            msg[u].w = f0[u].w * f1[u].w;
        }

        // 4 interleaved 64-lane butterflies (latency pipelined)
        #pragma unroll
        for (int off = 32; off; off >>= 1) {
            #pragma unroll
            for (int u = 0; u < 4; ++u) pv[u] += __shfl_xor(pv[u], off);
        }

        #pragma unroll
        for (int u = 0; u < 4; ++u) {
            const float var_mean = pv[u] * (1.f / (float)Dn);
            const float att = 1.f / (1.f + expf(-(waw * var_mean + wab)));
            neigh.x += att * msg[u].x;
            neigh.y += att * msg[u].y;
            neigh.z += att * msg[u].z;
            neigh.w += att * msg[u].w;
        }
    }

    const float4 s = Xv[(size_t)nodes[ub] * (Dn / 4) + lane];
    float4 h;
    h.x = s.x + neigh.x; h.y = s.y + neigh.y;
    h.z = s.z + neigh.z; h.w = s.w + neigh.w;
    reinterpret_cast<float4*>(h_out)[(size_t)b * (Dn / 4) + lane] = h;
}

// ---------------------------------------------------------------------------
// Stage 2: fused dual GEMM (fp32 vector — no fp32 MFMA on CDNA4).
//   enc2 = (1-beta)*relu(h @ lin_W^T + lin_b) + beta*(self @ skip_W^T)
// self rows are gathered on the fly: self[r] = X[nodes[r]].
// Tile 64x64, 256 threads, 4x4 per-thread microtile, BK=16.
// ---------------------------------------------------------------------------
#define BM 64
#define BN 64
#define BKs 16
#define LDT 68  // 64 + 4 pad: keeps float4 alignment, spreads banks

__global__ __launch_bounds__(256) void enc_gemm(
    const float* __restrict__ hA, const int* __restrict__ nodes,
    const float* __restrict__ X,
    const float* __restrict__ linW, const float* __restrict__ linb,
    const float* __restrict__ skipW, const float* __restrict__ beta_p,
    float* __restrict__ enc2, int M)
{
    __shared__ float Ats1[BKs][LDT];  // h tile, [k][row]
    __shared__ float Ats2[BKs][LDT];  // self tile, [k][row]
    __shared__ float Bts1[BKs][LDT];  // lin_W tile, [k][col]
    __shared__ float Bts2[BKs][LDT];  // skip_W tile, [k][col]

    const int tid = threadIdx.x;
    const int tx = tid & 15;    // col quad 0..15
    const int ty = tid >> 4;    // row quad 0..15
    const int row0 = blockIdx.x * BM;
    const int col0 = blockIdx.y * BN;

    const int lr = tid >> 2;    // 0..63 : tile row (A) / tile col (B)
    const int lc = tid & 3;     // 0..3  : k-quad

    const int arow = row0 + lr;
    const bool arow_ok = arow < M;
    const int self_row = arow_ok ? nodes[arow] : 0;

    float acc1[4][4] = {{0.f}}, acc2[4][4] = {{0.f}};

    for (int k0 = 0; k0 < Dn; k0 += BKs) {
        float4 a1v = make_float4(0.f, 0.f, 0.f, 0.f);
        float4 a2v = make_float4(0.f, 0.f, 0.f, 0.f);
        if (arow_ok) {
            a1v = *reinterpret_cast<const float4*>(hA + (size_t)arow * Dn + k0 + lc * 4);
            a2v = *reinterpret_cast<const float4*>(X + (size_t)self_row * Dn + k0 + lc * 4);
        }
        const float4 b1v = *reinterpret_cast<const float4*>(linW + (size_t)(col0 + lr) * Dn + k0 + lc * 4);
        const float4 b2v = *reinterpret_cast<const float4*>(skipW + (size_t)(col0 + lr) * Dn + k0 + lc * 4);

        __syncthreads();  // previous iteration finished reading LDS
        Ats1[lc * 4 + 0][lr] = a1v.x; Ats1[lc * 4 + 1][lr] = a1v.y;
        Ats1[lc * 4 + 2][lr] = a1v.z; Ats1[lc * 4 + 3][lr] = a1v.w;
        Ats2[lc * 4 + 0][lr] = a2v.x; Ats2[lc * 4 + 1][lr] = a2v.y;
        Ats2[lc * 4 + 2][lr] = a2v.z; Ats2[lc * 4 + 3][lr] = a2v.w;
        Bts1[lc * 4 + 0][lr] = b1v.x; Bts1[lc * 4 + 1][lr] = b1v.y;
        Bts1[lc * 4 + 2][lr] = b1v.z; Bts1[lc * 4 + 3][lr] = b1v.w;
        Bts2[lc * 4 + 0][lr] = b2v.x; Bts2[lc * 4 + 1][lr] = b2v.y;
        Bts2[lc * 4 + 2][lr] = b2v.z; Bts2[lc * 4 + 3][lr] = b2v.w;
        __syncthreads();

        #pragma unroll
        for (int kk = 0; kk < BKs; ++kk) {
            const float4 a1 = *reinterpret_cast<const float4*>(&Ats1[kk][ty * 4]);
            const float4 a2 = *reinterpret_cast<const float4*>(&Ats2[kk][ty * 4]);
            const float4 b1 = *reinterpret_cast<const float4*>(&Bts1[kk][tx * 4]);
            const float4 b2 = *reinterpret_cast<const float4*>(&Bts2[kk][tx * 4]);
            const float a1a[4] = {a1.x, a1.y, a1.z, a1.w};
            const float a2a[4] = {a2.x, a2.y, a2.z, a2.w};
            const float b1a[4] = {b1.x, b1.y, b1.z, b1.w};
            const float b2a[4] = {b2.x, b2.y, b2.z, b2.w};
            #pragma unroll
            for (int i = 0; i < 4; ++i)
                #pragma unroll
                for (int j = 0; j < 4; ++j) {
                    acc1[i][j] = fmaf(a1a[i], b1a[j], acc1[i][j]);
                    acc2[i][j] = fmaf(a2a[i], b2a[j], acc2[i][j]);
                }
        }
    }

    const float beta = beta_p[0];
    const float omb = 1.f - beta;
    #pragma unroll
    for (int i = 0; i < 4; ++i) {
        const int r = row0 + ty * 4 + i;
        if (r >= M) continue;
        #pragma unroll
        for (int j = 0; j < 4; ++j) {
            const int c = col0 + tx * 4 + j;
            float c1 = acc1[i][j] + linb[c];
            c1 = fmaxf(c1, 0.f);
            enc2[(size_t)r * Hn + c] = omb * c1 + beta * acc2[i][j];
        }
    }
}

// ---------------------------------------------------------------------------
// Stage 3: classifier + log_softmax. One wave per node b.
// v2: 8 classes per butterfly round (interleaved shfl chains instead of 40
// serial 6-level reduces).
// ---------------------------------------------------------------------------
__global__ __launch_bounds__(256) void cls_kernel(
    const float* __restrict__ enc2, const float* __restrict__ clsW,
    const float* __restrict__ clsb, float* __restrict__ out, int B)
{
    const int wave = threadIdx.x >> 6;
    const int lane = threadIdx.x & 63;
    const int b = blockIdx.x * 4 + wave;
    if (b >= B) return;

    const float4 e = reinterpret_cast<const float4*>(enc2 + (size_t)b * Hn)[lane];
    const float4* __restrict__ clsWv = reinterpret_cast<const float4*>(clsW);

    float mylogit = -INFINITY;
    #pragma unroll
    for (int c0 = 0; c0 < Cn; c0 += 8) {
        float p[8];
        #pragma unroll
        for (int u = 0; u < 8; ++u) {
            const float4 wv = clsWv[(size_t)(c0 + u) * (Hn / 4) + lane];
            p[u] = e.x * wv.x + e.y * wv.y + e.z * wv.z + e.w * wv.w;
        }
        #pragma unroll
        for (int off = 32; off; off >>= 1) {
            #pragma unroll
            for (int u = 0; u < 8; ++u) p[u] += __shfl_xor(p[u], off);
        }
        #pragma unroll
        for (int u = 0; u < 8; ++u)
            if (lane == c0 + u) mylogit = p[u];   // compile-time index -> cndmask
    }
    if (lane < Cn) mylogit += clsb[lane];

    float mx = mylogit;
    #pragma unroll
    for (int off = 32; off; off >>= 1) mx = fmaxf(mx, __shfl_xor(mx, off));
    float ex = (lane < Cn) ? expf(mylogit - mx) : 0.f;
    float se = ex;
    #pragma unroll
    for (int off = 32; off; off >>= 1) se += __shfl_xor(se, off);
    const float lse = logf(se);

    if (lane < Cn) out[(size_t)b * Cn + lane] = mylogit - mx - lse;
}

// ---------------------------------------------------------------------------
extern "C" void kernel_launch(void* const* d_in, const int* in_sizes, int n_in,
                              void* d_out, int out_size, void* d_ws, size_t ws_size,
                              hipStream_t stream) {
    const int*   nodes     = (const int*)d_in[0];
    const int*   structure = (const int*)d_in[1];
    const float* X         = (const float*)d_in[2];
    const float* beta      = (const float*)d_in[3];
    const float* waw       = (const float*)d_in[4];
    const float* wab       = (const float*)d_in[5];
    const float* linW      = (const float*)d_in[6];
    const float* linb      = (const float*)d_in[7];
    const float* skipW     = (const float*)d_in[8];
    const float* clsW      = (const float*)d_in[9];
    const float* clsb      = (const float*)d_in[10];
    float* out = (float*)d_out;

    const int B = in_sizes[0];

    float* h    = (float*)d_ws;                       // [B, D]
    float* enc2 = h + (size_t)B * Dn;                 // [B, H]

    // Stage 1: message passing -> h
    mp_kernel<<<(B + 3) / 4, 256, 0, stream>>>(nodes, structure, X, waw, wab, h, B);

    // Stage 2: fused dual GEMM -> enc2
    dim3 g2((B + BM - 1) / BM, Hn / BN);
    enc_gemm<<<g2, 256, 0, stream>>>(h, nodes, X, linW, linb, skipW, beta, enc2, B);

    // Stage 3: classifier + log_softmax -> out
    cls_kernel<<<(B + 3) / 4, 256, 0, stream>>>(enc2, clsW, clsb, out, B);
}

// Round 3
// 235.517 us; speedup vs baseline: 1.1954x; 1.1833x over previous
//
#include <hip/hip_runtime.h>
#include <hip/hip_bf16.h>
#include <math.h>

// Problem constants (from reference)
#define Dn 256     // feature dim
#define En 16      // hyperedges per node
#define Kn 3       // nodes per hyperedge
#define Hn 256     // hidden dim
#define Cn 40      // classes

static __device__ __forceinline__ float bf2f(unsigned short u) {
    return __uint_as_float(((unsigned)u) << 16);
}
static __device__ __forceinline__ unsigned pack2bf(float a, float b) {
    __hip_bfloat16 ha = __float2bfloat16(a);
    __hip_bfloat16 hb = __float2bfloat16(b);
    unsigned short ua = *reinterpret_cast<unsigned short*>(&ha);
    unsigned short ub = *reinterpret_cast<unsigned short*>(&hb);
    return (unsigned)ua | ((unsigned)ub << 16);
}

// ---------------------------------------------------------------------------
// Stage 0: X fp32 -> bf16 copy (halves the gather traffic of stage 1).
// Each thread converts 8 consecutive floats: 32B read, 16B write.
// ---------------------------------------------------------------------------
__global__ __launch_bounds__(256) void x_to_bf16(
    const float* __restrict__ X, uint4* __restrict__ Xb, int total8)
{
    const int t = blockIdx.x * 256 + threadIdx.x;
    if (t >= total8) return;
    const float4* __restrict__ Xv = reinterpret_cast<const float4*>(X);
    const float4 a = Xv[(size_t)t * 2 + 0];
    const float4 b = Xv[(size_t)t * 2 + 1];
    uint4 o;
    o.x = pack2bf(a.x, a.y);
    o.y = pack2bf(a.z, a.w);
    o.z = pack2bf(b.x, b.y);
    o.w = pack2bf(b.z, b.w);
    Xb[t] = o;
}

// ---------------------------------------------------------------------------
// Stage 1 (bf16 path): message passing. One wave per node b; lane owns 4 dims.
// Gathers come from the bf16 copy (512B/row); self row stays fp32 (exact).
// ---------------------------------------------------------------------------
__global__ __launch_bounds__(256) void mp_kernel_bf(
    const int* __restrict__ nodes, const int* __restrict__ structure,
    const float* __restrict__ X, const uint2* __restrict__ Xb,
    const float* __restrict__ waw_p, const float* __restrict__ wab_p,
    float* __restrict__ h_out, int B)
{
    const int wave = threadIdx.x >> 6;
    const int lane = threadIdx.x & 63;
    const int b = blockIdx.x * 4 + wave;
    if (b >= B) return;
    const int ub = __builtin_amdgcn_readfirstlane(b);  // wave-uniform

    const float waw = waw_p[0];
    const float wab = wab_p[0];

    float4 neigh = make_float4(0.f, 0.f, 0.f, 0.f);
    const int* st = structure + (size_t)ub * (En * Kn);

    #pragma unroll 1
    for (int g = 0; g < En / 4; ++g) {
        int idx[12];
        #pragma unroll
        for (int u = 0; u < 12; ++u) idx[u] = st[g * 12 + u];

        // 12 independent 512B row gathers in flight (uint2 per lane)
        uint2 r0[4], r1[4], r2[4];
        #pragma unroll
        for (int u = 0; u < 4; ++u) {
            r0[u] = Xb[(size_t)idx[u * 3 + 0] * (Dn / 4) + lane];
            r1[u] = Xb[(size_t)idx[u * 3 + 1] * (Dn / 4) + lane];
            r2[u] = Xb[(size_t)idx[u * 3 + 2] * (Dn / 4) + lane];
        }

        float pv[4];
        float4 msg[4];
        #pragma unroll
        for (int u = 0; u < 4; ++u) {
            float4 f0, f1, f2;
            f0.x = bf2f((unsigned short)(r0[u].x & 0xffff));
            f0.y = bf2f((unsigned short)(r0[u].x >> 16));
            f0.z = bf2f((unsigned short)(r0[u].y & 0xffff));
            f0.w = bf2f((unsigned short)(r0[u].y >> 16));
            f1.x = bf2f((unsigned short)(r1[u].x & 0xffff));
            f1.y = bf2f((unsigned short)(r1[u].x >> 16));
            f1.z = bf2f((unsigned short)(r1[u].y & 0xffff));
            f1.w = bf2f((unsigned short)(r1[u].y >> 16));
            f2.x = bf2f((unsigned short)(r2[u].x & 0xffff));
            f2.y = bf2f((unsigned short)(r2[u].x >> 16));
            f2.z = bf2f((unsigned short)(r2[u].y & 0xffff));
            f2.w = bf2f((unsigned short)(r2[u].y >> 16));

            float s = 0.f;
            {
                float a, bb, c, m;
                a = f0.x; bb = f1.x; c = f2.x;
                m = (a + bb + c) * (1.f / 3.f);
                s += (a * a + bb * bb + c * c) * (1.f / 3.f) - m * m;
                a = f0.y; bb = f1.y; c = f2.y;
                m = (a + bb + c) * (1.f / 3.f);
                s += (a * a + bb * bb + c * c) * (1.f / 3.f) - m * m;
                a = f0.z; bb = f1.z; c = f2.z;
                m = (a + bb + c) * (1.f / 3.f);
                s += (a * a + bb * bb + c * c) * (1.f / 3.f) - m * m;
                a = f0.w; bb = f1.w; c = f2.w;
                m = (a + bb + c) * (1.f / 3.f);
                s += (a * a + bb * bb + c * c) * (1.f / 3.f) - m * m;
            }
            pv[u] = s;
            msg[u].x = f0.x * f1.x;
            msg[u].y = f0.y * f1.y;
            msg[u].z = f0.z * f1.z;
            msg[u].w = f0.w * f1.w;
        }

        #pragma unroll
        for (int off = 32; off; off >>= 1) {
            #pragma unroll
            for (int u = 0; u < 4; ++u) pv[u] += __shfl_xor(pv[u], off);
        }

        #pragma unroll
        for (int u = 0; u < 4; ++u) {
            const float var_mean = pv[u] * (1.f / (float)Dn);
            const float att = 1.f / (1.f + expf(-(waw * var_mean + wab)));
            neigh.x += att * msg[u].x;
            neigh.y += att * msg[u].y;
            neigh.z += att * msg[u].z;
            neigh.w += att * msg[u].w;
        }
    }

    const float4 s = reinterpret_cast<const float4*>(X)[(size_t)nodes[ub] * (Dn / 4) + lane];
    float4 h;
    h.x = s.x + neigh.x; h.y = s.y + neigh.y;
    h.z = s.z + neigh.z; h.w = s.w + neigh.w;
    reinterpret_cast<float4*>(h_out)[(size_t)b * (Dn / 4) + lane] = h;
}

// ---------------------------------------------------------------------------
// Stage 1 (fp32 fallback, used only if ws_size can't hold the bf16 copy).
// ---------------------------------------------------------------------------
__global__ __launch_bounds__(256) void mp_kernel_f32(
    const int* __restrict__ nodes, const int* __restrict__ structure,
    const float* __restrict__ X, const float* __restrict__ waw_p,
    const float* __restrict__ wab_p, float* __restrict__ h_out, int B)
{
    const int wave = threadIdx.x >> 6;
    const int lane = threadIdx.x & 63;
    const int b = blockIdx.x * 4 + wave;
    if (b >= B) return;
    const int ub = __builtin_amdgcn_readfirstlane(b);

    const float waw = waw_p[0];
    const float wab = wab_p[0];
    const float4* __restrict__ Xv = reinterpret_cast<const float4*>(X);

    float4 neigh = make_float4(0.f, 0.f, 0.f, 0.f);
    const int* st = structure + (size_t)ub * (En * Kn);

    #pragma unroll 1
    for (int e = 0; e < En; ++e) {
        const int i0 = st[e * 3 + 0];
        const int i1 = st[e * 3 + 1];
        const int i2 = st[e * 3 + 2];
        const float4 f0 = Xv[(size_t)i0 * (Dn / 4) + lane];
        const float4 f1 = Xv[(size_t)i1 * (Dn / 4) + lane];
        const float4 f2 = Xv[(size_t)i2 * (Dn / 4) + lane];
        float pv = 0.f;
        {
            float a, bb, c, m;
            a = f0.x; bb = f1.x; c = f2.x;
            m = (a + bb + c) * (1.f / 3.f);
            pv += (a * a + bb * bb + c * c) * (1.f / 3.f) - m * m;
            a = f0.y; bb = f1.y; c = f2.y;
            m = (a + bb + c) * (1.f / 3.f);
            pv += (a * a + bb * bb + c * c) * (1.f / 3.f) - m * m;
            a = f0.z; bb = f1.z; c = f2.z;
            m = (a + bb + c) * (1.f / 3.f);
            pv += (a * a + bb * bb + c * c) * (1.f / 3.f) - m * m;
            a = f0.w; bb = f1.w; c = f2.w;
            m = (a + bb + c) * (1.f / 3.f);
            pv += (a * a + bb * bb + c * c) * (1.f / 3.f) - m * m;
        }
        #pragma unroll
        for (int off = 32; off; off >>= 1) pv += __shfl_xor(pv, off);
        const float var_mean = pv * (1.f / (float)Dn);
        const float att = 1.f / (1.f + expf(-(waw * var_mean + wab)));
        neigh.x += att * f0.x * f1.x;
        neigh.y += att * f0.y * f1.y;
        neigh.z += att * f0.z * f1.z;
        neigh.w += att * f0.w * f1.w;
    }

    const float4 s = Xv[(size_t)nodes[ub] * (Dn / 4) + lane];
    float4 h;
    h.x = s.x + neigh.x; h.y = s.y + neigh.y;
    h.z = s.z + neigh.z; h.w = s.w + neigh.w;
    reinterpret_cast<float4*>(h_out)[(size_t)b * (Dn / 4) + lane] = h;
}

// ---------------------------------------------------------------------------
// Stage 2: fused dual GEMM (fp32 vector — no fp32 MFMA on CDNA4).
//   enc2 = (1-beta)*relu(h @ lin_W^T + lin_b) + beta*(self @ skip_W^T)
// ---------------------------------------------------------------------------
#define BM 64
#define BN 64
#define BKs 16
#define LDT 68

__global__ __launch_bounds__(256) void enc_gemm(
    const float* __restrict__ hA, const int* __restrict__ nodes,
    const float* __restrict__ X,
    const float* __restrict__ linW, const float* __restrict__ linb,
    const float* __restrict__ skipW, const float* __restrict__ beta_p,
    float* __restrict__ enc2, int M)
{
    __shared__ float Ats1[BKs][LDT];
    __shared__ float Ats2[BKs][LDT];
    __shared__ float Bts1[BKs][LDT];
    __shared__ float Bts2[BKs][LDT];

    const int tid = threadIdx.x;
    const int tx = tid & 15;
    const int ty = tid >> 4;
    const int row0 = blockIdx.x * BM;
    const int col0 = blockIdx.y * BN;

    const int lr = tid >> 2;
    const int lc = tid & 3;

    const int arow = row0 + lr;
    const bool arow_ok = arow < M;
    const int self_row = arow_ok ? nodes[arow] : 0;

    float acc1[4][4] = {{0.f}}, acc2[4][4] = {{0.f}};

    for (int k0 = 0; k0 < Dn; k0 += BKs) {
        float4 a1v = make_float4(0.f, 0.f, 0.f, 0.f);
        float4 a2v = make_float4(0.f, 0.f, 0.f, 0.f);
        if (arow_ok) {
            a1v = *reinterpret_cast<const float4*>(hA + (size_t)arow * Dn + k0 + lc * 4);
            a2v = *reinterpret_cast<const float4*>(X + (size_t)self_row * Dn + k0 + lc * 4);
        }
        const float4 b1v = *reinterpret_cast<const float4*>(linW + (size_t)(col0 + lr) * Dn + k0 + lc * 4);
        const float4 b2v = *reinterpret_cast<const float4*>(skipW + (size_t)(col0 + lr) * Dn + k0 + lc * 4);

        __syncthreads();
        Ats1[lc * 4 + 0][lr] = a1v.x; Ats1[lc * 4 + 1][lr] = a1v.y;
        Ats1[lc * 4 + 2][lr] = a1v.z; Ats1[lc * 4 + 3][lr] = a1v.w;
        Ats2[lc * 4 + 0][lr] = a2v.x; Ats2[lc * 4 + 1][lr] = a2v.y;
        Ats2[lc * 4 + 2][lr] = a2v.z; Ats2[lc * 4 + 3][lr] = a2v.w;
        Bts1[lc * 4 + 0][lr] = b1v.x; Bts1[lc * 4 + 1][lr] = b1v.y;
        Bts1[lc * 4 + 2][lr] = b1v.z; Bts1[lc * 4 + 3][lr] = b1v.w;
        Bts2[lc * 4 + 0][lr] = b2v.x; Bts2[lc * 4 + 1][lr] = b2v.y;
        Bts2[lc * 4 + 2][lr] = b2v.z; Bts2[lc * 4 + 3][lr] = b2v.w;
        __syncthreads();

        #pragma unroll
        for (int kk = 0; kk < BKs; ++kk) {
            const float4 a1 = *reinterpret_cast<const float4*>(&Ats1[kk][ty * 4]);
            const float4 a2 = *reinterpret_cast<const float4*>(&Ats2[kk][ty * 4]);
            const float4 b1 = *reinterpret_cast<const float4*>(&Bts1[kk][tx * 4]);
            const float4 b2 = *reinterpret_cast<const float4*>(&Bts2[kk][tx * 4]);
            const float a1a[4] = {a1.x, a1.y, a1.z, a1.w};
            const float a2a[4] = {a2.x, a2.y, a2.z, a2.w};
            const float b1a[4] = {b1.x, b1.y, b1.z, b1.w};
            const float b2a[4] = {b2.x, b2.y, b2.z, b2.w};
            #pragma unroll
            for (int i = 0; i < 4; ++i)
                #pragma unroll
                for (int j = 0; j < 4; ++j) {
                    acc1[i][j] = fmaf(a1a[i], b1a[j], acc1[i][j]);
                    acc2[i][j] = fmaf(a2a[i], b2a[j], acc2[i][j]);
                }
        }
    }

    const float beta = beta_p[0];
    const float omb = 1.f - beta;
    #pragma unroll
    for (int i = 0; i < 4; ++i) {
        const int r = row0 + ty * 4 + i;
        if (r >= M) continue;
        #pragma unroll
        for (int j = 0; j < 4; ++j) {
            const int c = col0 + tx * 4 + j;
            float c1 = acc1[i][j] + linb[c];
            c1 = fmaxf(c1, 0.f);
            enc2[(size_t)r * Hn + c] = omb * c1 + beta * acc2[i][j];
        }
    }
}

// ---------------------------------------------------------------------------
// Stage 3: classifier + log_softmax. One wave per node b, 8 classes per
// butterfly round.
// ---------------------------------------------------------------------------
__global__ __launch_bounds__(256) void cls_kernel(
    const float* __restrict__ enc2, const float* __restrict__ clsW,
    const float* __restrict__ clsb, float* __restrict__ out, int B)
{
    const int wave = threadIdx.x >> 6;
    const int lane = threadIdx.x & 63;
    const int b = blockIdx.x * 4 + wave;
    if (b >= B) return;

    const float4 e = reinterpret_cast<const float4*>(enc2 + (size_t)b * Hn)[lane];
    const float4* __restrict__ clsWv = reinterpret_cast<const float4*>(clsW);

    float mylogit = -INFINITY;
    #pragma unroll
    for (int c0 = 0; c0 < Cn; c0 += 8) {
        float p[8];
        #pragma unroll
        for (int u = 0; u < 8; ++u) {
            const float4 wv = clsWv[(size_t)(c0 + u) * (Hn / 4) + lane];
            p[u] = e.x * wv.x + e.y * wv.y + e.z * wv.z + e.w * wv.w;
        }
        #pragma unroll
        for (int off = 32; off; off >>= 1) {
            #pragma unroll
            for (int u = 0; u < 8; ++u) p[u] += __shfl_xor(p[u], off);
        }
        #pragma unroll
        for (int u = 0; u < 8; ++u)
            if (lane == c0 + u) mylogit = p[u];
    }
    if (lane < Cn) mylogit += clsb[lane];

    float mx = mylogit;
    #pragma unroll
    for (int off = 32; off; off >>= 1) mx = fmaxf(mx, __shfl_xor(mx, off));
    float ex = (lane < Cn) ? expf(mylogit - mx) : 0.f;
    float se = ex;
    #pragma unroll
    for (int off = 32; off; off >>= 1) se += __shfl_xor(se, off);
    const float lse = logf(se);

    if (lane < Cn) out[(size_t)b * Cn + lane] = mylogit - mx - lse;
}

// ---------------------------------------------------------------------------
extern "C" void kernel_launch(void* const* d_in, const int* in_sizes, int n_in,
                              void* d_out, int out_size, void* d_ws, size_t ws_size,
                              hipStream_t stream) {
    const int*   nodes     = (const int*)d_in[0];
    const int*   structure = (const int*)d_in[1];
    const float* X         = (const float*)d_in[2];
    const float* beta      = (const float*)d_in[3];
    const float* waw       = (const float*)d_in[4];
    const float* wab       = (const float*)d_in[5];
    const float* linW      = (const float*)d_in[6];
    const float* linb      = (const float*)d_in[7];
    const float* skipW     = (const float*)d_in[8];
    const float* clsW      = (const float*)d_in[9];
    const float* clsb      = (const float*)d_in[10];
    float* out = (float*)d_out;

    const int B = in_sizes[0];
    const int Ntot = in_sizes[2];            // N * D floats
    const int N = Ntot / Dn;

    float* h    = (float*)d_ws;                       // [B, D] fp32
    float* enc2 = h + (size_t)B * Dn;                 // [B, H] fp32
    void*  xb   = (void*)(enc2 + (size_t)B * Hn);     // [N, D] bf16

    const size_t need = (size_t)B * Dn * 4 + (size_t)B * Hn * 4 + (size_t)Ntot * 2;

    if (ws_size >= need) {
        // Stage 0: bf16 copy of X
        const int total8 = Ntot / 8;
        x_to_bf16<<<(total8 + 255) / 256, 256, 0, stream>>>(X, (uint4*)xb, total8);
        // Stage 1: message passing (bf16 gathers)
        mp_kernel_bf<<<(B + 3) / 4, 256, 0, stream>>>(
            nodes, structure, X, (const uint2*)xb, waw, wab, h, B);
    } else {
        mp_kernel_f32<<<(B + 3) / 4, 256, 0, stream>>>(nodes, structure, X, waw, wab, h, B);
    }

    // Stage 2: fused dual GEMM -> enc2
    dim3 g2((B + BM - 1) / BM, Hn / BN);
    enc_gemm<<<g2, 256, 0, stream>>>(h, nodes, X, linW, linb, skipW, beta, enc2, B);

    // Stage 3: classifier + log_softmax -> out
    cls_kernel<<<(B + 3) / 4, 256, 0, stream>>>(enc2, clsW, clsb, out, B);
}

// Round 4
// 206.763 us; speedup vs baseline: 1.3617x; 1.1391x over previous
//
#include <hip/hip_runtime.h>
#include <hip/hip_bf16.h>
#include <math.h>

// Problem constants (from reference)
#define Dn 256     // feature dim
#define En 16      // hyperedges per node
#define Kn 3       // nodes per hyperedge
#define Hn 256     // hidden dim
#define Cn 40      // classes

typedef __attribute__((ext_vector_type(8))) short bf16x8;
typedef __attribute__((ext_vector_type(4))) float f32x4;

static __device__ __forceinline__ float bf2f(unsigned short u) {
    return __uint_as_float(((unsigned)u) << 16);
}
static __device__ __forceinline__ unsigned pack2bf(float a, float b) {
    __hip_bfloat16 ha = __float2bfloat16(a);
    __hip_bfloat16 hb = __float2bfloat16(b);
    unsigned short ua = *reinterpret_cast<unsigned short*>(&ha);
    unsigned short ub = *reinterpret_cast<unsigned short*>(&hb);
    return (unsigned)ua | ((unsigned)ub << 16);
}

// ---------------------------------------------------------------------------
// Stage 0: generic fp32 -> bf16 conversion (X, lin_W, skip_W).
// Each thread converts 8 consecutive floats: 32B read, 16B write.
// ---------------------------------------------------------------------------
__global__ __launch_bounds__(256) void f32_to_bf16(
    const float* __restrict__ in, uint4* __restrict__ out, int total8)
{
    const int t = blockIdx.x * 256 + threadIdx.x;
    if (t >= total8) return;
    const float4* __restrict__ iv = reinterpret_cast<const float4*>(in);
    const float4 a = iv[(size_t)t * 2 + 0];
    const float4 b = iv[(size_t)t * 2 + 1];
    uint4 o;
    o.x = pack2bf(a.x, a.y);
    o.y = pack2bf(a.z, a.w);
    o.z = pack2bf(b.x, b.y);
    o.w = pack2bf(b.z, b.w);
    out[t] = o;
}

// ---------------------------------------------------------------------------
// Stage 1 (bf16 path): message passing. One wave per node b; lane owns 4 dims.
// Gathers from the bf16 copy (512B/row); self row read fp32 (exact).
// Output h written as bf16 (feeds the MFMA GEMM directly).
// ---------------------------------------------------------------------------
__global__ __launch_bounds__(256) void mp_kernel_bf(
    const int* __restrict__ nodes, const int* __restrict__ structure,
    const float* __restrict__ X, const uint2* __restrict__ Xb,
    const float* __restrict__ waw_p, const float* __restrict__ wab_p,
    unsigned short* __restrict__ h_out, int B)
{
    const int wave = threadIdx.x >> 6;
    const int lane = threadIdx.x & 63;
    const int b = blockIdx.x * 4 + wave;
    if (b >= B) return;
    const int ub = __builtin_amdgcn_readfirstlane(b);  // wave-uniform

    const float waw = waw_p[0];
    const float wab = wab_p[0];

    float4 neigh = make_float4(0.f, 0.f, 0.f, 0.f);
    const int* st = structure + (size_t)ub * (En * Kn);

    #pragma unroll 1
    for (int g = 0; g < En / 4; ++g) {
        int idx[12];
        #pragma unroll
        for (int u = 0; u < 12; ++u) idx[u] = st[g * 12 + u];

        uint2 r0[4], r1[4], r2[4];
        #pragma unroll
        for (int u = 0; u < 4; ++u) {
            r0[u] = Xb[(size_t)idx[u * 3 + 0] * (Dn / 4) + lane];
            r1[u] = Xb[(size_t)idx[u * 3 + 1] * (Dn / 4) + lane];
            r2[u] = Xb[(size_t)idx[u * 3 + 2] * (Dn / 4) + lane];
        }

        float pv[4];
        float4 msg[4];
        #pragma unroll
        for (int u = 0; u < 4; ++u) {
            float4 f0, f1, f2;
            f0.x = bf2f((unsigned short)(r0[u].x & 0xffff));
            f0.y = bf2f((unsigned short)(r0[u].x >> 16));
            f0.z = bf2f((unsigned short)(r0[u].y & 0xffff));
            f0.w = bf2f((unsigned short)(r0[u].y >> 16));
            f1.x = bf2f((unsigned short)(r1[u].x & 0xffff));
            f1.y = bf2f((unsigned short)(r1[u].x >> 16));
            f1.z = bf2f((unsigned short)(r1[u].y & 0xffff));
            f1.w = bf2f((unsigned short)(r1[u].y >> 16));
            f2.x = bf2f((unsigned short)(r2[u].x & 0xffff));
            f2.y = bf2f((unsigned short)(r2[u].x >> 16));
            f2.z = bf2f((unsigned short)(r2[u].y & 0xffff));
            f2.w = bf2f((unsigned short)(r2[u].y >> 16));

            float s = 0.f;
            {
                float a, bb, c, m;
                a = f0.x; bb = f1.x; c = f2.x;
                m = (a + bb + c) * (1.f / 3.f);
                s += (a * a + bb * bb + c * c) * (1.f / 3.f) - m * m;
                a = f0.y; bb = f1.y; c = f2.y;
                m = (a + bb + c) * (1.f / 3.f);
                s += (a * a + bb * bb + c * c) * (1.f / 3.f) - m * m;
                a = f0.z; bb = f1.z; c = f2.z;
                m = (a + bb + c) * (1.f / 3.f);
                s += (a * a + bb * bb + c * c) * (1.f / 3.f) - m * m;
                a = f0.w; bb = f1.w; c = f2.w;
                m = (a + bb + c) * (1.f / 3.f);
                s += (a * a + bb * bb + c * c) * (1.f / 3.f) - m * m;
            }
            pv[u] = s;
            msg[u].x = f0.x * f1.x;
            msg[u].y = f0.y * f1.y;
            msg[u].z = f0.z * f1.z;
            msg[u].w = f0.w * f1.w;
        }

        #pragma unroll
        for (int off = 32; off; off >>= 1) {
            #pragma unroll
            for (int u = 0; u < 4; ++u) pv[u] += __shfl_xor(pv[u], off);
        }

        #pragma unroll
        for (int u = 0; u < 4; ++u) {
            const float var_mean = pv[u] * (1.f / (float)Dn);
            const float att = 1.f / (1.f + expf(-(waw * var_mean + wab)));
            neigh.x += att * msg[u].x;
            neigh.y += att * msg[u].y;
            neigh.z += att * msg[u].z;
            neigh.w += att * msg[u].w;
        }
    }

    const float4 s = reinterpret_cast<const float4*>(X)[(size_t)nodes[ub] * (Dn / 4) + lane];
    uint2 o;
    o.x = pack2bf(s.x + neigh.x, s.y + neigh.y);
    o.y = pack2bf(s.z + neigh.z, s.w + neigh.w);
    reinterpret_cast<uint2*>(h_out)[(size_t)b * (Dn / 4) + lane] = o;
}

// ---------------------------------------------------------------------------
// Stage 2 (MFMA): dual GEMM on the matrix pipe, no LDS.
//   enc2 = (1-beta)*relu(h @ lin_W^T + lin_b) + beta*(self @ skip_W^T)
// Block: 256 threads = 4 waves. Wave w: rows [row0+w*16, +16), cols [col0, +64).
// Fragment layout (gfx950 16x16x32 bf16, verified):
//   A: row = lane&15, k = (lane>>4)*8 + i   (8 contiguous bf16 -> 16B load)
//   B: col = lane&15, k = (lane>>4)*8 + i   (weights row-major [H,D] -> direct)
//   D: col = lane&15, row = (lane>>4)*4 + r
// ---------------------------------------------------------------------------
__global__ __launch_bounds__(256) void enc_gemm_mfma(
    const unsigned short* __restrict__ hB,     // [M,256] bf16
    const int* __restrict__ nodes,
    const unsigned short* __restrict__ Xb,     // [N,256] bf16
    const unsigned short* __restrict__ linWb, const float* __restrict__ linb,
    const unsigned short* __restrict__ skipWb, const float* __restrict__ beta_p,
    float* __restrict__ enc2, int M)
{
    const int w  = threadIdx.x >> 6;
    const int l  = threadIdx.x & 63;
    const int lr = l & 15;
    const int kg = l >> 4;
    const int row0 = blockIdx.x * 64 + w * 16;
    const int col0 = blockIdx.y * 64;

    const int arow = row0 + lr;
    const int arc  = arow < M ? arow : (M - 1);
    const int srow = nodes[arc];

    f32x4 acc1[4], acc2[4];
    #pragma unroll
    for (int n = 0; n < 4; ++n) {
        acc1[n] = (f32x4){0.f, 0.f, 0.f, 0.f};
        acc2[n] = (f32x4){0.f, 0.f, 0.f, 0.f};
    }

    #pragma unroll 2
    for (int k0 = 0; k0 < Dn; k0 += 32) {
        const int ko = k0 + kg * 8;
        const bf16x8 a1 = *reinterpret_cast<const bf16x8*>(hB + (size_t)arc  * Dn + ko);
        const bf16x8 a2 = *reinterpret_cast<const bf16x8*>(Xb + (size_t)srow * Dn + ko);
        #pragma unroll
        for (int n = 0; n < 4; ++n) {
            const bf16x8 b1 = *reinterpret_cast<const bf16x8*>(linWb  + (size_t)(col0 + n * 16 + lr) * Dn + ko);
            const bf16x8 b2 = *reinterpret_cast<const bf16x8*>(skipWb + (size_t)(col0 + n * 16 + lr) * Dn + ko);
            acc1[n] = __builtin_amdgcn_mfma_f32_16x16x32_bf16(a1, b1, acc1[n], 0, 0, 0);
            acc2[n] = __builtin_amdgcn_mfma_f32_16x16x32_bf16(a2, b2, acc2[n], 0, 0, 0);
        }
    }

    const float beta = beta_p[0];
    const float omb = 1.f - beta;
    #pragma unroll
    for (int n = 0; n < 4; ++n) {
        const int col = col0 + n * 16 + lr;
        const float bias = linb[col];
        #pragma unroll
        for (int r = 0; r < 4; ++r) {
            const int row = row0 + kg * 4 + r;
            if (row < M) {
                const float c1 = fmaxf(acc1[n][r] + bias, 0.f);
                enc2[(size_t)row * Hn + col] = omb * c1 + beta * acc2[n][r];
            }
        }
    }
}

// ---------------------------------------------------------------------------
// fp32 fallback path (only if ws_size too small for bf16 copies)
// ---------------------------------------------------------------------------
__global__ __launch_bounds__(256) void mp_kernel_f32(
    const int* __restrict__ nodes, const int* __restrict__ structure,
    const float* __restrict__ X, const float* __restrict__ waw_p,
    const float* __restrict__ wab_p, float* __restrict__ h_out, int B)
{
    const int wave = threadIdx.x >> 6;
    const int lane = threadIdx.x & 63;
    const int b = blockIdx.x * 4 + wave;
    if (b >= B) return;
    const int ub = __builtin_amdgcn_readfirstlane(b);

    const float waw = waw_p[0];
    const float wab = wab_p[0];
    const float4* __restrict__ Xv = reinterpret_cast<const float4*>(X);

    float4 neigh = make_float4(0.f, 0.f, 0.f, 0.f);
    const int* st = structure + (size_t)ub * (En * Kn);

    #pragma unroll 1
    for (int e = 0; e < En; ++e) {
        const int i0 = st[e * 3 + 0];
        const int i1 = st[e * 3 + 1];
        const int i2 = st[e * 3 + 2];
        const float4 f0 = Xv[(size_t)i0 * (Dn / 4) + lane];
        const float4 f1 = Xv[(size_t)i1 * (Dn / 4) + lane];
        const float4 f2 = Xv[(size_t)i2 * (Dn / 4) + lane];
        float pv = 0.f;
        {
            float a, bb, c, m;
            a = f0.x; bb = f1.x; c = f2.x;
            m = (a + bb + c) * (1.f / 3.f);
            pv += (a * a + bb * bb + c * c) * (1.f / 3.f) - m * m;
            a = f0.y; bb = f1.y; c = f2.y;
            m = (a + bb + c) * (1.f / 3.f);
            pv += (a * a + bb * bb + c * c) * (1.f / 3.f) - m * m;
            a = f0.z; bb = f1.z; c = f2.z;
            m = (a + bb + c) * (1.f / 3.f);
            pv += (a * a + bb * bb + c * c) * (1.f / 3.f) - m * m;
            a = f0.w; bb = f1.w; c = f2.w;
            m = (a + bb + c) * (1.f / 3.f);
            pv += (a * a + bb * bb + c * c) * (1.f / 3.f) - m * m;
        }
        #pragma unroll
        for (int off = 32; off; off >>= 1) pv += __shfl_xor(pv, off);
        const float var_mean = pv * (1.f / (float)Dn);
        const float att = 1.f / (1.f + expf(-(waw * var_mean + wab)));
        neigh.x += att * f0.x * f1.x;
        neigh.y += att * f0.y * f1.y;
        neigh.z += att * f0.z * f1.z;
        neigh.w += att * f0.w * f1.w;
    }

    const float4 s = Xv[(size_t)nodes[ub] * (Dn / 4) + lane];
    float4 h;
    h.x = s.x + neigh.x; h.y = s.y + neigh.y;
    h.z = s.z + neigh.z; h.w = s.w + neigh.w;
    reinterpret_cast<float4*>(h_out)[(size_t)b * (Dn / 4) + lane] = h;
}

#define BM 64
#define BN 64
#define BKs 16
#define LDT 68

__global__ __launch_bounds__(256) void enc_gemm_f32(
    const float* __restrict__ hA, const int* __restrict__ nodes,
    const float* __restrict__ X,
    const float* __restrict__ linW, const float* __restrict__ linb,
    const float* __restrict__ skipW, const float* __restrict__ beta_p,
    float* __restrict__ enc2, int M)
{
    __shared__ float Ats1[BKs][LDT];
    __shared__ float Ats2[BKs][LDT];
    __shared__ float Bts1[BKs][LDT];
    __shared__ float Bts2[BKs][LDT];

    const int tid = threadIdx.x;
    const int tx = tid & 15;
    const int ty = tid >> 4;
    const int row0 = blockIdx.x * BM;
    const int col0 = blockIdx.y * BN;

    const int lr = tid >> 2;
    const int lc = tid & 3;

    const int arow = row0 + lr;
    const bool arow_ok = arow < M;
    const int self_row = arow_ok ? nodes[arow] : 0;

    float acc1[4][4] = {{0.f}}, acc2[4][4] = {{0.f}};

    for (int k0 = 0; k0 < Dn; k0 += BKs) {
        float4 a1v = make_float4(0.f, 0.f, 0.f, 0.f);
        float4 a2v = make_float4(0.f, 0.f, 0.f, 0.f);
        if (arow_ok) {
            a1v = *reinterpret_cast<const float4*>(hA + (size_t)arow * Dn + k0 + lc * 4);
            a2v = *reinterpret_cast<const float4*>(X + (size_t)self_row * Dn + k0 + lc * 4);
        }
        const float4 b1v = *reinterpret_cast<const float4*>(linW + (size_t)(col0 + lr) * Dn + k0 + lc * 4);
        const float4 b2v = *reinterpret_cast<const float4*>(skipW + (size_t)(col0 + lr) * Dn + k0 + lc * 4);

        __syncthreads();
        Ats1[lc * 4 + 0][lr] = a1v.x; Ats1[lc * 4 + 1][lr] = a1v.y;
        Ats1[lc * 4 + 2][lr] = a1v.z; Ats1[lc * 4 + 3][lr] = a1v.w;
        Ats2[lc * 4 + 0][lr] = a2v.x; Ats2[lc * 4 + 1][lr] = a2v.y;
        Ats2[lc * 4 + 2][lr] = a2v.z; Ats2[lc * 4 + 3][lr] = a2v.w;
        Bts1[lc * 4 + 0][lr] = b1v.x; Bts1[lc * 4 + 1][lr] = b1v.y;
        Bts1[lc * 4 + 2][lr] = b1v.z; Bts1[lc * 4 + 3][lr] = b1v.w;
        Bts2[lc * 4 + 0][lr] = b2v.x; Bts2[lc * 4 + 1][lr] = b2v.y;
        Bts2[lc * 4 + 2][lr] = b2v.z; Bts2[lc * 4 + 3][lr] = b2v.w;
        __syncthreads();

        #pragma unroll
        for (int kk = 0; kk < BKs; ++kk) {
            const float4 a1 = *reinterpret_cast<const float4*>(&Ats1[kk][ty * 4]);
            const float4 a2 = *reinterpret_cast<const float4*>(&Ats2[kk][ty * 4]);
            const float4 b1 = *reinterpret_cast<const float4*>(&Bts1[kk][tx * 4]);
            const float4 b2 = *reinterpret_cast<const float4*>(&Bts2[kk][tx * 4]);
            const float a1a[4] = {a1.x, a1.y, a1.z, a1.w};
            const float a2a[4] = {a2.x, a2.y, a2.z, a2.w};
            const float b1a[4] = {b1.x, b1.y, b1.z, b1.w};
            const float b2a[4] = {b2.x, b2.y, b2.z, b2.w};
            #pragma unroll
            for (int i = 0; i < 4; ++i)
                #pragma unroll
                for (int j = 0; j < 4; ++j) {
                    acc1[i][j] = fmaf(a1a[i], b1a[j], acc1[i][j]);
                    acc2[i][j] = fmaf(a2a[i], b2a[j], acc2[i][j]);
                }
        }
    }

    const float beta = beta_p[0];
    const float omb = 1.f - beta;
    #pragma unroll
    for (int i = 0; i < 4; ++i) {
        const int r = row0 + ty * 4 + i;
        if (r >= M) continue;
        #pragma unroll
        for (int j = 0; j < 4; ++j) {
            const int c = col0 + tx * 4 + j;
            float c1 = acc1[i][j] + linb[c];
            c1 = fmaxf(c1, 0.f);
            enc2[(size_t)r * Hn + c] = omb * c1 + beta * acc2[i][j];
        }
    }
}

// ---------------------------------------------------------------------------
// Stage 3: classifier + log_softmax. One wave per node b, 8 classes per
// butterfly round.
// ---------------------------------------------------------------------------
__global__ __launch_bounds__(256) void cls_kernel(
    const float* __restrict__ enc2, const float* __restrict__ clsW,
    const float* __restrict__ clsb, float* __restrict__ out, int B)
{
    const int wave = threadIdx.x >> 6;
    const int lane = threadIdx.x & 63;
    const int b = blockIdx.x * 4 + wave;
    if (b >= B) return;

    const float4 e = reinterpret_cast<const float4*>(enc2 + (size_t)b * Hn)[lane];
    const float4* __restrict__ clsWv = reinterpret_cast<const float4*>(clsW);

    float mylogit = -INFINITY;
    #pragma unroll
    for (int c0 = 0; c0 < Cn; c0 += 8) {
        float p[8];
        #pragma unroll
        for (int u = 0; u < 8; ++u) {
            const float4 wv = clsWv[(size_t)(c0 + u) * (Hn / 4) + lane];
            p[u] = e.x * wv.x + e.y * wv.y + e.z * wv.z + e.w * wv.w;
        }
        #pragma unroll
        for (int off = 32; off; off >>= 1) {
            #pragma unroll
            for (int u = 0; u < 8; ++u) p[u] += __shfl_xor(p[u], off);
        }
        #pragma unroll
        for (int u = 0; u < 8; ++u)
            if (lane == c0 + u) mylogit = p[u];
    }
    if (lane < Cn) mylogit += clsb[lane];

    float mx = mylogit;
    #pragma unroll
    for (int off = 32; off; off >>= 1) mx = fmaxf(mx, __shfl_xor(mx, off));
    float ex = (lane < Cn) ? expf(mylogit - mx) : 0.f;
    float se = ex;
    #pragma unroll
    for (int off = 32; off; off >>= 1) se += __shfl_xor(se, off);
    const float lse = logf(se);

    if (lane < Cn) out[(size_t)b * Cn + lane] = mylogit - mx - lse;
}

// ---------------------------------------------------------------------------
extern "C" void kernel_launch(void* const* d_in, const int* in_sizes, int n_in,
                              void* d_out, int out_size, void* d_ws, size_t ws_size,
                              hipStream_t stream) {
    const int*   nodes     = (const int*)d_in[0];
    const int*   structure = (const int*)d_in[1];
    const float* X         = (const float*)d_in[2];
    const float* beta      = (const float*)d_in[3];
    const float* waw       = (const float*)d_in[4];
    const float* wab       = (const float*)d_in[5];
    const float* linW      = (const float*)d_in[6];
    const float* linb      = (const float*)d_in[7];
    const float* skipW     = (const float*)d_in[8];
    const float* clsW      = (const float*)d_in[9];
    const float* clsb      = (const float*)d_in[10];
    float* out = (float*)d_out;

    const int B = in_sizes[0];
    const int Ntot = in_sizes[2];            // N * D floats

    // ws layout (bf16 path):
    //   enc2  [B,H]  fp32
    //   h_bf  [B,D]  bf16
    //   Xb    [N,D]  bf16
    //   linWb [H,D]  bf16
    //   skipWb[H,D]  bf16
    float*          enc2   = (float*)d_ws;
    unsigned short* h_bf   = (unsigned short*)(enc2 + (size_t)B * Hn);
    unsigned short* Xb     = h_bf + (size_t)B * Dn;
    unsigned short* linWb  = Xb + (size_t)Ntot;
    unsigned short* skipWb = linWb + (size_t)Hn * Dn;

    const size_t need = (size_t)B * Hn * 4 + (size_t)B * Dn * 2 +
                        (size_t)Ntot * 2 + (size_t)Hn * Dn * 2 * 2;

    if (ws_size >= need) {
        // Stage 0: bf16 conversions
        const int x8 = Ntot / 8;
        f32_to_bf16<<<(x8 + 255) / 256, 256, 0, stream>>>(X, (uint4*)Xb, x8);
        const int w8 = (Hn * Dn) / 8;
        f32_to_bf16<<<(w8 + 255) / 256, 256, 0, stream>>>(linW, (uint4*)linWb, w8);
        f32_to_bf16<<<(w8 + 255) / 256, 256, 0, stream>>>(skipW, (uint4*)skipWb, w8);

        // Stage 1: message passing (bf16 gathers) -> h_bf
        mp_kernel_bf<<<(B + 3) / 4, 256, 0, stream>>>(
            nodes, structure, X, (const uint2*)Xb, waw, wab, h_bf, B);

        // Stage 2: MFMA dual GEMM -> enc2
        dim3 g2((B + 63) / 64, Hn / 64);
        enc_gemm_mfma<<<g2, 256, 0, stream>>>(
            h_bf, nodes, Xb, linWb, linb, skipWb, beta, enc2, B);
    } else {
        float* hf = (float*)(enc2 + (size_t)B * Hn);  // reuse space as fp32 h
        mp_kernel_f32<<<(B + 3) / 4, 256, 0, stream>>>(nodes, structure, X, waw, wab, hf, B);
        dim3 g2((B + BM - 1) / BM, Hn / BN);
        enc_gemm_f32<<<g2, 256, 0, stream>>>(hf, nodes, X, linW, linb, skipW, beta, enc2, B);
    }

    // Stage 3: classifier + log_softmax -> out
    cls_kernel<<<(B + 3) / 4, 256, 0, stream>>>(enc2, clsW, clsb, out, B);
}

// Round 5
// 163.442 us; speedup vs baseline: 1.7226x; 1.2651x over previous
//
#include <hip/hip_runtime.h>
#include <hip/hip_bf16.h>
#include <math.h>

// Problem constants (from reference)
#define Dn 256     // feature dim
#define En 16      // hyperedges per node
#define Kn 3       // nodes per hyperedge
#define Hn 256     // hidden dim
#define Cn 40      // classes
#define CnP 48     // classes padded to 3x16 for MFMA col tiles

typedef __attribute__((ext_vector_type(8))) short bf16x8;
typedef __attribute__((ext_vector_type(4))) float f32x4;

static __device__ __forceinline__ float bf2f(unsigned short u) {
    return __uint_as_float(((unsigned)u) << 16);
}
static __device__ __forceinline__ unsigned short f2bfbits(float v) {
    __hip_bfloat16 hb = __float2bfloat16(v);
    return *reinterpret_cast<unsigned short*>(&hb);
}
static __device__ __forceinline__ unsigned pack2bf(float a, float b) {
    return (unsigned)f2bfbits(a) | ((unsigned)f2bfbits(b) << 16);
}

// ---------------------------------------------------------------------------
// Stage 0: merged fp32 -> bf16 conversion: X, lin_W, skip_W, cls_W (padded
// to 48 rows with zeros). One launch; each thread converts 8 floats.
// ---------------------------------------------------------------------------
__global__ __launch_bounds__(256) void conv_all(
    const float* __restrict__ X, const float* __restrict__ linW,
    const float* __restrict__ skipW, const float* __restrict__ clsW,
    uint4* __restrict__ Xb, uint4* __restrict__ linWb,
    uint4* __restrict__ skipWb, uint4* __restrict__ clsWb,
    int x8, int w8)
{
    int t = blockIdx.x * 256 + threadIdx.x;
    const int c8 = (CnP * Hn) / 8;
    if (t < x8) {
        const float4* iv = reinterpret_cast<const float4*>(X);
        const float4 a = iv[(size_t)t * 2 + 0];
        const float4 b = iv[(size_t)t * 2 + 1];
        Xb[t] = (uint4){pack2bf(a.x, a.y), pack2bf(a.z, a.w),
                        pack2bf(b.x, b.y), pack2bf(b.z, b.w)};
        return;
    }
    t -= x8;
    if (t < w8) {
        const float4* iv = reinterpret_cast<const float4*>(linW);
        const float4 a = iv[(size_t)t * 2 + 0];
        const float4 b = iv[(size_t)t * 2 + 1];
        linWb[t] = (uint4){pack2bf(a.x, a.y), pack2bf(a.z, a.w),
                           pack2bf(b.x, b.y), pack2bf(b.z, b.w)};
        return;
    }
    t -= w8;
    if (t < w8) {
        const float4* iv = reinterpret_cast<const float4*>(skipW);
        const float4 a = iv[(size_t)t * 2 + 0];
        const float4 b = iv[(size_t)t * 2 + 1];
        skipWb[t] = (uint4){pack2bf(a.x, a.y), pack2bf(a.z, a.w),
                            pack2bf(b.x, b.y), pack2bf(b.z, b.w)};
        return;
    }
    t -= w8;
    if (t < c8) {
        const int row = t >> 5;               // 32 groups of 8 per 256-row
        if (row < Cn) {
            const float4* iv = reinterpret_cast<const float4*>(clsW);
            const float4 a = iv[(size_t)t * 2 + 0];
            const float4 b = iv[(size_t)t * 2 + 1];
            clsWb[t] = (uint4){pack2bf(a.x, a.y), pack2bf(a.z, a.w),
                               pack2bf(b.x, b.y), pack2bf(b.z, b.w)};
        } else {
            clsWb[t] = (uint4){0u, 0u, 0u, 0u};
        }
    }
}

// ---------------------------------------------------------------------------
// Stage 1 (bf16): message passing. One wave per node b; lane owns 4 dims.
// Variance via S2-C identity: sum_d var_d = 2*(S2 - C)/9,
//   S2 = sum(a^2+b^2+c^2), C = sum(ab+ac+bc)   (6 FMA/dim).
// Self row read from bf16 copy (h is rounded to bf16 anyway).
// ---------------------------------------------------------------------------
__global__ __launch_bounds__(256) void mp_kernel_bf(
    const int* __restrict__ nodes, const int* __restrict__ structure,
    const uint2* __restrict__ Xb,
    const float* __restrict__ waw_p, const float* __restrict__ wab_p,
    uint2* __restrict__ h_out, int B)
{
    const int wave = threadIdx.x >> 6;
    const int lane = threadIdx.x & 63;
    const int b = blockIdx.x * 4 + wave;
    if (b >= B) return;
    const int ub = __builtin_amdgcn_readfirstlane(b);  // wave-uniform

    const float waw = waw_p[0];
    const float wab = wab_p[0];

    float4 neigh = make_float4(0.f, 0.f, 0.f, 0.f);
    const int* st = structure + (size_t)ub * (En * Kn);

    #pragma unroll 1
    for (int g = 0; g < En / 4; ++g) {
        int idx[12];
        #pragma unroll
        for (int u = 0; u < 12; ++u) idx[u] = st[g * 12 + u];

        uint2 r0[4], r1[4], r2[4];
        #pragma unroll
        for (int u = 0; u < 4; ++u) {
            r0[u] = Xb[(size_t)idx[u * 3 + 0] * (Dn / 4) + lane];
            r1[u] = Xb[(size_t)idx[u * 3 + 1] * (Dn / 4) + lane];
            r2[u] = Xb[(size_t)idx[u * 3 + 2] * (Dn / 4) + lane];
        }

        float pv[4];
        float4 msg[4];
        #pragma unroll
        for (int u = 0; u < 4; ++u) {
            float4 f0, f1, f2;
            f0.x = bf2f((unsigned short)(r0[u].x & 0xffff));
            f0.y = bf2f((unsigned short)(r0[u].x >> 16));
            f0.z = bf2f((unsigned short)(r0[u].y & 0xffff));
            f0.w = bf2f((unsigned short)(r0[u].y >> 16));
            f1.x = bf2f((unsigned short)(r1[u].x & 0xffff));
            f1.y = bf2f((unsigned short)(r1[u].x >> 16));
            f1.z = bf2f((unsigned short)(r1[u].y & 0xffff));
            f1.w = bf2f((unsigned short)(r1[u].y >> 16));
            f2.x = bf2f((unsigned short)(r2[u].x & 0xffff));
            f2.y = bf2f((unsigned short)(r2[u].x >> 16));
            f2.z = bf2f((unsigned short)(r2[u].y & 0xffff));
            f2.w = bf2f((unsigned short)(r2[u].y >> 16));

            float s2 = 0.f, cr = 0.f, tt;
            s2 = fmaf(f0.x, f0.x, s2); s2 = fmaf(f1.x, f1.x, s2); s2 = fmaf(f2.x, f2.x, s2);
            tt = f1.x + f2.x; cr = fmaf(f0.x, tt, cr); cr = fmaf(f1.x, f2.x, cr);
            s2 = fmaf(f0.y, f0.y, s2); s2 = fmaf(f1.y, f1.y, s2); s2 = fmaf(f2.y, f2.y, s2);
            tt = f1.y + f2.y; cr = fmaf(f0.y, tt, cr); cr = fmaf(f1.y, f2.y, cr);
            s2 = fmaf(f0.z, f0.z, s2); s2 = fmaf(f1.z, f1.z, s2); s2 = fmaf(f2.z, f2.z, s2);
            tt = f1.z + f2.z; cr = fmaf(f0.z, tt, cr); cr = fmaf(f1.z, f2.z, cr);
            s2 = fmaf(f0.w, f0.w, s2); s2 = fmaf(f1.w, f1.w, s2); s2 = fmaf(f2.w, f2.w, s2);
            tt = f1.w + f2.w; cr = fmaf(f0.w, tt, cr); cr = fmaf(f1.w, f2.w, cr);

            pv[u] = s2 - cr;
            msg[u].x = f0.x * f1.x;
            msg[u].y = f0.y * f1.y;
            msg[u].z = f0.z * f1.z;
            msg[u].w = f0.w * f1.w;
        }

        #pragma unroll
        for (int off = 32; off; off >>= 1) {
            #pragma unroll
            for (int u = 0; u < 4; ++u) pv[u] += __shfl_xor(pv[u], off);
        }

        #pragma unroll
        for (int u = 0; u < 4; ++u) {
            const float var_mean = pv[u] * (2.f / (9.f * (float)Dn));
            const float att = 1.f / (1.f + expf(-(waw * var_mean + wab)));
            neigh.x += att * msg[u].x;
            neigh.y += att * msg[u].y;
            neigh.z += att * msg[u].z;
            neigh.w += att * msg[u].w;
        }
    }

    const uint2 sv = Xb[(size_t)nodes[ub] * (Dn / 4) + lane];
    const float sx = bf2f((unsigned short)(sv.x & 0xffff));
    const float sy = bf2f((unsigned short)(sv.x >> 16));
    const float sz = bf2f((unsigned short)(sv.y & 0xffff));
    const float sw = bf2f((unsigned short)(sv.y >> 16));
    uint2 o;
    o.x = pack2bf(sx + neigh.x, sy + neigh.y);
    o.y = pack2bf(sz + neigh.z, sw + neigh.w);
    h_out[(size_t)b * (Dn / 4) + lane] = o;
}

// ---------------------------------------------------------------------------
// Stage 2 (MFMA): dual GEMM on the matrix pipe, no LDS. Output bf16.
//   enc2 = (1-beta)*relu(h @ lin_W^T + lin_b) + beta*(self @ skip_W^T)
// Wave w: rows [row0+w*16, +16), cols [col0, +64). K fully unrolled so the
// compiler can hoist loads across K-steps.
// ---------------------------------------------------------------------------
__global__ __launch_bounds__(256) void enc_gemm_mfma(
    const unsigned short* __restrict__ hB,     // [M,256] bf16
    const int* __restrict__ nodes,
    const unsigned short* __restrict__ Xb,     // [N,256] bf16
    const unsigned short* __restrict__ linWb, const float* __restrict__ linb,
    const unsigned short* __restrict__ skipWb, const float* __restrict__ beta_p,
    unsigned short* __restrict__ enc2b, int M)
{
    const int w  = threadIdx.x >> 6;
    const int l  = threadIdx.x & 63;
    const int lr = l & 15;
    const int kg = l >> 4;
    const int row0 = blockIdx.x * 64 + w * 16;
    const int col0 = blockIdx.y * 64;

    const int arow = row0 + lr;
    const int arc  = arow < M ? arow : (M - 1);
    const int srow = nodes[arc];

    f32x4 acc1[4], acc2[4];
    #pragma unroll
    for (int n = 0; n < 4; ++n) {
        acc1[n] = (f32x4){0.f, 0.f, 0.f, 0.f};
        acc2[n] = (f32x4){0.f, 0.f, 0.f, 0.f};
    }

    #pragma unroll
    for (int k0 = 0; k0 < Dn; k0 += 32) {
        const int ko = k0 + kg * 8;
        const bf16x8 a1 = *reinterpret_cast<const bf16x8*>(hB + (size_t)arc  * Dn + ko);
        const bf16x8 a2 = *reinterpret_cast<const bf16x8*>(Xb + (size_t)srow * Dn + ko);
        #pragma unroll
        for (int n = 0; n < 4; ++n) {
            const bf16x8 b1 = *reinterpret_cast<const bf16x8*>(linWb  + (size_t)(col0 + n * 16 + lr) * Dn + ko);
            const bf16x8 b2 = *reinterpret_cast<const bf16x8*>(skipWb + (size_t)(col0 + n * 16 + lr) * Dn + ko);
            acc1[n] = __builtin_amdgcn_mfma_f32_16x16x32_bf16(a1, b1, acc1[n], 0, 0, 0);
            acc2[n] = __builtin_amdgcn_mfma_f32_16x16x32_bf16(a2, b2, acc2[n], 0, 0, 0);
        }
    }

    const float beta = beta_p[0];
    const float omb = 1.f - beta;
    #pragma unroll
    for (int n = 0; n < 4; ++n) {
        const int col = col0 + n * 16 + lr;
        const float bias = linb[col];
        #pragma unroll
        for (int r = 0; r < 4; ++r) {
            const int row = row0 + kg * 4 + r;
            if (row < M) {
                const float c1 = fmaxf(acc1[n][r] + bias, 0.f);
                enc2b[(size_t)row * Hn + col] = f2bfbits(omb * c1 + beta * acc2[n][r]);
            }
        }
    }
}

// ---------------------------------------------------------------------------
// Stage 3 (MFMA): classifier + log_softmax.
// Block: 64 rows, 4 waves (wave w: rows w*16..+16). 3 col tiles cover 48
// padded cols (pad weights are zero; pad bias = -INF so exp()=0).
// Row-wise softmax: logits for one row live in 16 lanes x 3 tiles -> 4-level
// xor butterfly within each 16-lane group.
// ---------------------------------------------------------------------------
__global__ __launch_bounds__(256) void cls_mfma(
    const unsigned short* __restrict__ enc2b,   // [M,256] bf16
    const unsigned short* __restrict__ clsWb,   // [48,256] bf16 (zero-padded)
    const float* __restrict__ clsb, float* __restrict__ out, int M)
{
    const int w  = threadIdx.x >> 6;
    const int l  = threadIdx.x & 63;
    const int lr = l & 15;
    const int kg = l >> 4;
    const int row0 = blockIdx.x * 64 + w * 16;
    const int arc = (row0 + lr) < M ? (row0 + lr) : (M - 1);

    f32x4 acc[3];
    #pragma unroll
    for (int t = 0; t < 3; ++t) acc[t] = (f32x4){0.f, 0.f, 0.f, 0.f};

    #pragma unroll
    for (int k0 = 0; k0 < Hn; k0 += 32) {
        const int ko = k0 + kg * 8;
        const bf16x8 a = *reinterpret_cast<const bf16x8*>(enc2b + (size_t)arc * Hn + ko);
        #pragma unroll
        for (int t = 0; t < 3; ++t) {
            const bf16x8 bb = *reinterpret_cast<const bf16x8*>(clsWb + (size_t)(t * 16 + lr) * Hn + ko);
            acc[t] = __builtin_amdgcn_mfma_f32_16x16x32_bf16(a, bb, acc[t], 0, 0, 0);
        }
    }

    // bias per column (pad cols -> -INF)
    float bias[3];
    #pragma unroll
    for (int t = 0; t < 3; ++t) {
        const int cb = t * 16 + lr;
        bias[t] = (cb < Cn) ? clsb[cb] : -INFINITY;
    }

    #pragma unroll
    for (int r = 0; r < 4; ++r) {
        float lg0 = acc[0][r] + bias[0];
        float lg1 = acc[1][r] + bias[1];
        float lg2 = acc[2][r] + bias[2];
        float mx = fmaxf(fmaxf(lg0, lg1), lg2);
        #pragma unroll
        for (int off = 8; off; off >>= 1) mx = fmaxf(mx, __shfl_xor(mx, off));
        float se = expf(lg0 - mx) + expf(lg1 - mx) + expf(lg2 - mx);
        #pragma unroll
        for (int off = 8; off; off >>= 1) se += __shfl_xor(se, off);
        const float lse = logf(se);

        const int row = row0 + kg * 4 + r;
        if (row < M) {
            if (lr < 8) out[(size_t)row * Cn + 32 + lr] = lg2 - mx - lse;
            out[(size_t)row * Cn + lr]       = lg0 - mx - lse;
            out[(size_t)row * Cn + 16 + lr]  = lg1 - mx - lse;
        }
    }
}

// ---------------------------------------------------------------------------
// fp32 fallback path (only if ws_size too small for bf16 copies)
// ---------------------------------------------------------------------------
__global__ __launch_bounds__(256) void mp_kernel_f32(
    const int* __restrict__ nodes, const int* __restrict__ structure,
    const float* __restrict__ X, const float* __restrict__ waw_p,
    const float* __restrict__ wab_p, float* __restrict__ h_out, int B)
{
    const int wave = threadIdx.x >> 6;
    const int lane = threadIdx.x & 63;
    const int b = blockIdx.x * 4 + wave;
    if (b >= B) return;
    const int ub = __builtin_amdgcn_readfirstlane(b);

    const float waw = waw_p[0];
    const float wab = wab_p[0];
    const float4* __restrict__ Xv = reinterpret_cast<const float4*>(X);

    float4 neigh = make_float4(0.f, 0.f, 0.f, 0.f);
    const int* st = structure + (size_t)ub * (En * Kn);

    #pragma unroll 1
    for (int e = 0; e < En; ++e) {
        const int i0 = st[e * 3 + 0];
        const int i1 = st[e * 3 + 1];
        const int i2 = st[e * 3 + 2];
        const float4 f0 = Xv[(size_t)i0 * (Dn / 4) + lane];
        const float4 f1 = Xv[(size_t)i1 * (Dn / 4) + lane];
        const float4 f2 = Xv[(size_t)i2 * (Dn / 4) + lane];
        float pv = 0.f;
        {
            float a, bb, c, m;
            a = f0.x; bb = f1.x; c = f2.x;
            m = (a + bb + c) * (1.f / 3.f);
            pv += (a * a + bb * bb + c * c) * (1.f / 3.f) - m * m;
            a = f0.y; bb = f1.y; c = f2.y;
            m = (a + bb + c) * (1.f / 3.f);
            pv += (a * a + bb * bb + c * c) * (1.f / 3.f) - m * m;
            a = f0.z; bb = f1.z; c = f2.z;
            m = (a + bb + c) * (1.f / 3.f);
            pv += (a * a + bb * bb + c * c) * (1.f / 3.f) - m * m;
            a = f0.w; bb = f1.w; c = f2.w;
            m = (a + bb + c) * (1.f / 3.f);
            pv += (a * a + bb * bb + c * c) * (1.f / 3.f) - m * m;
        }
        #pragma unroll
        for (int off = 32; off; off >>= 1) pv += __shfl_xor(pv, off);
        const float var_mean = pv * (1.f / (float)Dn);
        const float att = 1.f / (1.f + expf(-(waw * var_mean + wab)));
        neigh.x += att * f0.x * f1.x;
        neigh.y += att * f0.y * f1.y;
        neigh.z += att * f0.z * f1.z;
        neigh.w += att * f0.w * f1.w;
    }

    const float4 s = Xv[(size_t)nodes[ub] * (Dn / 4) + lane];
    float4 h;
    h.x = s.x + neigh.x; h.y = s.y + neigh.y;
    h.z = s.z + neigh.z; h.w = s.w + neigh.w;
    reinterpret_cast<float4*>(h_out)[(size_t)b * (Dn / 4) + lane] = h;
}

#define BM 64
#define BN 64
#define BKs 16
#define LDT 68

__global__ __launch_bounds__(256) void enc_gemm_f32(
    const float* __restrict__ hA, const int* __restrict__ nodes,
    const float* __restrict__ X,
    const float* __restrict__ linW, const float* __restrict__ linb,
    const float* __restrict__ skipW, const float* __restrict__ beta_p,
    float* __restrict__ enc2, int M)
{
    __shared__ float Ats1[BKs][LDT];
    __shared__ float Ats2[BKs][LDT];
    __shared__ float Bts1[BKs][LDT];
    __shared__ float Bts2[BKs][LDT];

    const int tid = threadIdx.x;
    const int tx = tid & 15;
    const int ty = tid >> 4;
    const int row0 = blockIdx.x * BM;
    const int col0 = blockIdx.y * BN;

    const int lr = tid >> 2;
    const int lc = tid & 3;

    const int arow = row0 + lr;
    const bool arow_ok = arow < M;
    const int self_row = arow_ok ? nodes[arow] : 0;

    float acc1[4][4] = {{0.f}}, acc2[4][4] = {{0.f}};

    for (int k0 = 0; k0 < Dn; k0 += BKs) {
        float4 a1v = make_float4(0.f, 0.f, 0.f, 0.f);
        float4 a2v = make_float4(0.f, 0.f, 0.f, 0.f);
        if (arow_ok) {
            a1v = *reinterpret_cast<const float4*>(hA + (size_t)arow * Dn + k0 + lc * 4);
            a2v = *reinterpret_cast<const float4*>(X + (size_t)self_row * Dn + k0 + lc * 4);
        }
        const float4 b1v = *reinterpret_cast<const float4*>(linW + (size_t)(col0 + lr) * Dn + k0 + lc * 4);
        const float4 b2v = *reinterpret_cast<const float4*>(skipW + (size_t)(col0 + lr) * Dn + k0 + lc * 4);

        __syncthreads();
        Ats1[lc * 4 + 0][lr] = a1v.x; Ats1[lc * 4 + 1][lr] = a1v.y;
        Ats1[lc * 4 + 2][lr] = a1v.z; Ats1[lc * 4 + 3][lr] = a1v.w;
        Ats2[lc * 4 + 0][lr] = a2v.x; Ats2[lc * 4 + 1][lr] = a2v.y;
        Ats2[lc * 4 + 2][lr] = a2v.z; Ats2[lc * 4 + 3][lr] = a2v.w;
        Bts1[lc * 4 + 0][lr] = b1v.x; Bts1[lc * 4 + 1][lr] = b1v.y;
        Bts1[lc * 4 + 2][lr] = b1v.z; Bts1[lc * 4 + 3][lr] = b1v.w;
        Bts2[lc * 4 + 0][lr] = b2v.x; Bts2[lc * 4 + 1][lr] = b2v.y;
        Bts2[lc * 4 + 2][lr] = b2v.z; Bts2[lc * 4 + 3][lr] = b2v.w;
        __syncthreads();

        #pragma unroll
        for (int kk = 0; kk < BKs; ++kk) {
            const float4 a1 = *reinterpret_cast<const float4*>(&Ats1[kk][ty * 4]);
            const float4 a2 = *reinterpret_cast<const float4*>(&Ats2[kk][ty * 4]);
            const float4 b1 = *reinterpret_cast<const float4*>(&Bts1[kk][tx * 4]);
            const float4 b2 = *reinterpret_cast<const float4*>(&Bts2[kk][tx * 4]);
            const float a1a[4] = {a1.x, a1.y, a1.z, a1.w};
            const float a2a[4] = {a2.x, a2.y, a2.z, a2.w};
            const float b1a[4] = {b1.x, b1.y, b1.z, b1.w};
            const float b2a[4] = {b2.x, b2.y, b2.z, b2.w};
            #pragma unroll
            for (int i = 0; i < 4; ++i)
                #pragma unroll
                for (int j = 0; j < 4; ++j) {
                    acc1[i][j] = fmaf(a1a[i], b1a[j], acc1[i][j]);
                    acc2[i][j] = fmaf(a2a[i], b2a[j], acc2[i][j]);
                }
        }
    }

    const float beta = beta_p[0];
    const float omb = 1.f - beta;
    #pragma unroll
    for (int i = 0; i < 4; ++i) {
        const int r = row0 + ty * 4 + i;
        if (r >= M) continue;
        #pragma unroll
        for (int j = 0; j < 4; ++j) {
            const int c = col0 + tx * 4 + j;
            float c1 = acc1[i][j] + linb[c];
            c1 = fmaxf(c1, 0.f);
            enc2[(size_t)r * Hn + c] = omb * c1 + beta * acc2[i][j];
        }
    }
}

__global__ __launch_bounds__(256) void cls_kernel_f32(
    const float* __restrict__ enc2, const float* __restrict__ clsW,
    const float* __restrict__ clsb, float* __restrict__ out, int B)
{
    const int wave = threadIdx.x >> 6;
    const int lane = threadIdx.x & 63;
    const int b = blockIdx.x * 4 + wave;
    if (b >= B) return;

    const float4 e = reinterpret_cast<const float4*>(enc2 + (size_t)b * Hn)[lane];
    const float4* __restrict__ clsWv = reinterpret_cast<const float4*>(clsW);

    float mylogit = -INFINITY;
    #pragma unroll
    for (int c0 = 0; c0 < Cn; c0 += 8) {
        float p[8];
        #pragma unroll
        for (int u = 0; u < 8; ++u) {
            const float4 wv = clsWv[(size_t)(c0 + u) * (Hn / 4) + lane];
            p[u] = e.x * wv.x + e.y * wv.y + e.z * wv.z + e.w * wv.w;
        }
        #pragma unroll
        for (int off = 32; off; off >>= 1) {
            #pragma unroll
            for (int u = 0; u < 8; ++u) p[u] += __shfl_xor(p[u], off);
        }
        #pragma unroll
        for (int u = 0; u < 8; ++u)
            if (lane == c0 + u) mylogit = p[u];
    }
    if (lane < Cn) mylogit += clsb[lane];

    float mx = mylogit;
    #pragma unroll
    for (int off = 32; off; off >>= 1) mx = fmaxf(mx, __shfl_xor(mx, off));
    float ex = (lane < Cn) ? expf(mylogit - mx) : 0.f;
    float se = ex;
    #pragma unroll
    for (int off = 32; off; off >>= 1) se += __shfl_xor(se, off);
    const float lse = logf(se);

    if (lane < Cn) out[(size_t)b * Cn + lane] = mylogit - mx - lse;
}

// ---------------------------------------------------------------------------
extern "C" void kernel_launch(void* const* d_in, const int* in_sizes, int n_in,
                              void* d_out, int out_size, void* d_ws, size_t ws_size,
                              hipStream_t stream) {
    const int*   nodes     = (const int*)d_in[0];
    const int*   structure = (const int*)d_in[1];
    const float* X         = (const float*)d_in[2];
    const float* beta      = (const float*)d_in[3];
    const float* waw       = (const float*)d_in[4];
    const float* wab       = (const float*)d_in[5];
    const float* linW      = (const float*)d_in[6];
    const float* linb      = (const float*)d_in[7];
    const float* skipW     = (const float*)d_in[8];
    const float* clsW      = (const float*)d_in[9];
    const float* clsb      = (const float*)d_in[10];
    float* out = (float*)d_out;

    const int B = in_sizes[0];
    const int Ntot = in_sizes[2];            // N * D floats

    // ws layout (bf16 path):
    //   enc2b  [B,H]   bf16
    //   h_bf   [B,D]   bf16
    //   Xb     [N,D]   bf16
    //   linWb  [H,D]   bf16
    //   skipWb [H,D]   bf16
    //   clsWb  [48,H]  bf16 (zero-padded)
    unsigned short* enc2b  = (unsigned short*)d_ws;
    unsigned short* h_bf   = enc2b + (size_t)B * Hn;
    unsigned short* Xb     = h_bf + (size_t)B * Dn;
    unsigned short* linWb  = Xb + (size_t)Ntot;
    unsigned short* skipWb = linWb + (size_t)Hn * Dn;
    unsigned short* clsWb  = skipWb + (size_t)Hn * Dn;

    const size_t need = ((size_t)B * Hn + (size_t)B * Dn + (size_t)Ntot +
                         (size_t)Hn * Dn * 2 + (size_t)CnP * Hn) * 2;

    if (ws_size >= need) {
        // Stage 0: one merged bf16 conversion launch
        const int x8 = Ntot / 8;
        const int w8 = (Hn * Dn) / 8;
        const int c8 = (CnP * Hn) / 8;
        const int G = x8 + 2 * w8 + c8;
        conv_all<<<(G + 255) / 256, 256, 0, stream>>>(
            X, linW, skipW, clsW,
            (uint4*)Xb, (uint4*)linWb, (uint4*)skipWb, (uint4*)clsWb, x8, w8);

        // Stage 1: message passing (bf16 gathers) -> h_bf
        mp_kernel_bf<<<(B + 3) / 4, 256, 0, stream>>>(
            nodes, structure, (const uint2*)Xb, waw, wab, (uint2*)h_bf, B);

        // Stage 2: MFMA dual GEMM -> enc2b (bf16)
        dim3 g2((B + 63) / 64, Hn / 64);
        enc_gemm_mfma<<<g2, 256, 0, stream>>>(
            h_bf, nodes, Xb, linWb, linb, skipWb, beta, enc2b, B);

        // Stage 3: MFMA classifier + log_softmax -> out
        cls_mfma<<<(B + 63) / 64, 256, 0, stream>>>(enc2b, clsWb, clsb, out, B);
    } else {
        float* enc2 = (float*)d_ws;
        float* hf   = enc2 + (size_t)B * Hn;
        mp_kernel_f32<<<(B + 3) / 4, 256, 0, stream>>>(nodes, structure, X, waw, wab, hf, B);
        dim3 g2((B + BM - 1) / BM, Hn / BN);
        enc_gemm_f32<<<g2, 256, 0, stream>>>(hf, nodes, X, linW, linb, skipW, beta, enc2, B);
        cls_kernel_f32<<<(B + 3) / 4, 256, 0, stream>>>(enc2, clsW, clsb, out, B);
    }
}

// Round 7
// 150.930 us; speedup vs baseline: 1.8654x; 1.0829x over previous
//
#include <hip/hip_runtime.h>
#include <hip/hip_bf16.h>
#include <math.h>

// Problem constants (from reference)
#define Dn 256     // feature dim
#define En 16      // hyperedges per node
#define Kn 3       // nodes per hyperedge
#define Hn 256     // hidden dim
#define Cn 40      // classes
#define CnP 48     // classes padded to 3x16 for MFMA col tiles

typedef __attribute__((ext_vector_type(8)))  short bf16x8;
typedef __attribute__((ext_vector_type(4)))  float f32x4;
typedef __attribute__((ext_vector_type(16))) float f32x16;

static __device__ __forceinline__ float bf2f(unsigned short u) {
    return __uint_as_float(((unsigned)u) << 16);
}
static __device__ __forceinline__ unsigned short f2bfbits(float v) {
    __hip_bfloat16 hb = __float2bfloat16(v);
    return *reinterpret_cast<unsigned short*>(&hb);
}
static __device__ __forceinline__ unsigned pack2bf(float a, float b) {
    return (unsigned)f2bfbits(a) | ((unsigned)f2bfbits(b) << 16);
}

// ---------------------------------------------------------------------------
// Stage 0: merged fp32 -> bf16 conversion: X, lin_W, skip_W, cls_W (padded
// to 48 rows with zeros). One launch; each thread converts 8 floats.
// ---------------------------------------------------------------------------
__global__ __launch_bounds__(256) void conv_all(
    const float* __restrict__ X, const float* __restrict__ linW,
    const float* __restrict__ skipW, const float* __restrict__ clsW,
    uint4* __restrict__ Xb, uint4* __restrict__ linWb,
    uint4* __restrict__ skipWb, uint4* __restrict__ clsWb,
    int x8, int w8)
{
    int t = blockIdx.x * 256 + threadIdx.x;
    const int c8 = (CnP * Hn) / 8;
    if (t < x8) {
        const float4* iv = reinterpret_cast<const float4*>(X);
        const float4 a = iv[(size_t)t * 2 + 0];
        const float4 b = iv[(size_t)t * 2 + 1];
        Xb[t] = (uint4){pack2bf(a.x, a.y), pack2bf(a.z, a.w),
                        pack2bf(b.x, b.y), pack2bf(b.z, b.w)};
        return;
    }
    t -= x8;
    if (t < w8) {
        const float4* iv = reinterpret_cast<const float4*>(linW);
        const float4 a = iv[(size_t)t * 2 + 0];
        const float4 b = iv[(size_t)t * 2 + 1];
        linWb[t] = (uint4){pack2bf(a.x, a.y), pack2bf(a.z, a.w),
                           pack2bf(b.x, b.y), pack2bf(b.z, b.w)};
        return;
    }
    t -= w8;
    if (t < w8) {
        const float4* iv = reinterpret_cast<const float4*>(skipW);
        const float4 a = iv[(size_t)t * 2 + 0];
        const float4 b = iv[(size_t)t * 2 + 1];
        skipWb[t] = (uint4){pack2bf(a.x, a.y), pack2bf(a.z, a.w),
                            pack2bf(b.x, b.y), pack2bf(b.z, b.w)};
        return;
    }
    t -= w8;
    if (t < c8) {
        const int row = t >> 5;               // 32 groups of 8 per 256-col row
        if (row < Cn) {
            const float4* iv = reinterpret_cast<const float4*>(clsW);
            const float4 a = iv[(size_t)t * 2 + 0];
            const float4 b = iv[(size_t)t * 2 + 1];
            clsWb[t] = (uint4){pack2bf(a.x, a.y), pack2bf(a.z, a.w),
                               pack2bf(b.x, b.y), pack2bf(b.z, b.w)};
        } else {
            clsWb[t] = (uint4){0u, 0u, 0u, 0u};
        }
    }
}

// ---------------------------------------------------------------------------
// Stage 1 (bf16): message passing. One wave per node b; lane owns 4 dims.
// Variance via S2-C identity: sum_d var_d = 2*(S2 - C)/9.
// Also streams the self row out (selfb) so enc_gemm reads it contiguously
// instead of re-gathering random rows at the 3.2 TB/s gather wall.
// ---------------------------------------------------------------------------
__global__ __launch_bounds__(256) void mp_kernel_bf(
    const int* __restrict__ nodes, const int* __restrict__ structure,
    const uint2* __restrict__ Xb,
    const float* __restrict__ waw_p, const float* __restrict__ wab_p,
    uint2* __restrict__ h_out, uint2* __restrict__ self_out, int B)
{
    const int wave = threadIdx.x >> 6;
    const int lane = threadIdx.x & 63;
    const int b = blockIdx.x * 4 + wave;
    if (b >= B) return;
    const int ub = __builtin_amdgcn_readfirstlane(b);  // wave-uniform

    const float waw = waw_p[0];
    const float wab = wab_p[0];

    float4 neigh = make_float4(0.f, 0.f, 0.f, 0.f);
    const int* st = structure + (size_t)ub * (En * Kn);

    #pragma unroll 1
    for (int g = 0; g < En / 4; ++g) {
        int idx[12];
        #pragma unroll
        for (int u = 0; u < 12; ++u) idx[u] = st[g * 12 + u];

        uint2 r0[4], r1[4], r2[4];
        #pragma unroll
        for (int u = 0; u < 4; ++u) {
            r0[u] = Xb[(size_t)idx[u * 3 + 0] * (Dn / 4) + lane];
            r1[u] = Xb[(size_t)idx[u * 3 + 1] * (Dn / 4) + lane];
            r2[u] = Xb[(size_t)idx[u * 3 + 2] * (Dn / 4) + lane];
        }

        float pv[4];
        float4 msg[4];
        #pragma unroll
        for (int u = 0; u < 4; ++u) {
            float4 f0, f1, f2;
            f0.x = bf2f((unsigned short)(r0[u].x & 0xffff));
            f0.y = bf2f((unsigned short)(r0[u].x >> 16));
            f0.z = bf2f((unsigned short)(r0[u].y & 0xffff));
            f0.w = bf2f((unsigned short)(r0[u].y >> 16));
            f1.x = bf2f((unsigned short)(r1[u].x & 0xffff));
            f1.y = bf2f((unsigned short)(r1[u].x >> 16));
            f1.z = bf2f((unsigned short)(r1[u].y & 0xffff));
            f1.w = bf2f((unsigned short)(r1[u].y >> 16));
            f2.x = bf2f((unsigned short)(r2[u].x & 0xffff));
            f2.y = bf2f((unsigned short)(r2[u].x >> 16));
            f2.z = bf2f((unsigned short)(r2[u].y & 0xffff));
            f2.w = bf2f((unsigned short)(r2[u].y >> 16));

            float s2 = 0.f, cr = 0.f, tt;
            s2 = fmaf(f0.x, f0.x, s2); s2 = fmaf(f1.x, f1.x, s2); s2 = fmaf(f2.x, f2.x, s2);
            tt = f1.x + f2.x; cr = fmaf(f0.x, tt, cr); cr = fmaf(f1.x, f2.x, cr);
            s2 = fmaf(f0.y, f0.y, s2); s2 = fmaf(f1.y, f1.y, s2); s2 = fmaf(f2.y, f2.y, s2);
            tt = f1.y + f2.y; cr = fmaf(f0.y, tt, cr); cr = fmaf(f1.y, f2.y, cr);
            s2 = fmaf(f0.z, f0.z, s2); s2 = fmaf(f1.z, f1.z, s2); s2 = fmaf(f2.z, f2.z, s2);
            tt = f1.z + f2.z; cr = fmaf(f0.z, tt, cr); cr = fmaf(f1.z, f2.z, cr);
            s2 = fmaf(f0.w, f0.w, s2); s2 = fmaf(f1.w, f1.w, s2); s2 = fmaf(f2.w, f2.w, s2);
            tt = f1.w + f2.w; cr = fmaf(f0.w, tt, cr); cr = fmaf(f1.w, f2.w, cr);

            pv[u] = s2 - cr;
            msg[u].x = f0.x * f1.x;
            msg[u].y = f0.y * f1.y;
            msg[u].z = f0.z * f1.z;
            msg[u].w = f0.w * f1.w;
        }

        #pragma unroll
        for (int off = 32; off; off >>= 1) {
            #pragma unroll
            for (int u = 0; u < 4; ++u) pv[u] += __shfl_xor(pv[u], off);
        }

        #pragma unroll
        for (int u = 0; u < 4; ++u) {
            const float var_mean = pv[u] * (2.f / (9.f * (float)Dn));
            const float att = 1.f / (1.f + expf(-(waw * var_mean + wab)));
            neigh.x += att * msg[u].x;
            neigh.y += att * msg[u].y;
            neigh.z += att * msg[u].z;
            neigh.w += att * msg[u].w;
        }
    }

    const uint2 sv = Xb[(size_t)nodes[ub] * (Dn / 4) + lane];
    self_out[(size_t)b * (Dn / 4) + lane] = sv;
    const float sx = bf2f((unsigned short)(sv.x & 0xffff));
    const float sy = bf2f((unsigned short)(sv.x >> 16));
    const float sz = bf2f((unsigned short)(sv.y & 0xffff));
    const float sw = bf2f((unsigned short)(sv.y >> 16));
    uint2 o;
    o.x = pack2bf(sx + neigh.x, sy + neigh.y);
    o.y = pack2bf(sz + neigh.z, sw + neigh.w);
    h_out[(size_t)b * (Dn / 4) + lane] = o;
}

// ---------------------------------------------------------------------------
// Stage 2 (MFMA 32x32x16): dual GEMM, no LDS, fragment-traffic optimized.
//   enc2 = (1-beta)*relu(h @ lin_W^T + lin_b) + beta*(self @ skip_W^T)
// Block 128x128 (4 waves, 2x2), wave tile 64x64 = 2x2 subtiles of 32x32.
// Per k-step (k=16): 8 fragment loads feed 8 MFMAs of 32768 FLOP each
// (31 B/kFLOP vs 78 for the 16x16 version). A reused over n, B over m.
// Layouts (gfx950): A row=lane&31, k=(lane>>5)*8+i ; B col=lane&31, same k;
// D col=lane&31, row=(reg&3)+8*(reg>>2)+4*(lane>>5).
// ---------------------------------------------------------------------------
__global__ __launch_bounds__(256, 2) void enc_gemm_mfma32(
    const unsigned short* __restrict__ hB,     // [M,256] bf16
    const unsigned short* __restrict__ selfB,  // [M,256] bf16
    const unsigned short* __restrict__ linWb, const float* __restrict__ linb,
    const unsigned short* __restrict__ skipWb, const float* __restrict__ beta_p,
    unsigned short* __restrict__ enc2b, int M)
{
    const int w  = threadIdx.x >> 6;
    const int l  = threadIdx.x & 63;
    const int wr = w >> 1, wc = w & 1;
    const int lr = l & 31;
    const int kh = l >> 5;
    const int row0 = blockIdx.x * 128 + wr * 64;
    const int col0 = blockIdx.y * 128 + wc * 64;

    int ar[2];
    ar[0] = row0 + lr;
    ar[1] = row0 + 32 + lr;
    ar[0] = ar[0] < M ? ar[0] : M - 1;
    ar[1] = ar[1] < M ? ar[1] : M - 1;
    const int bc0 = col0 + lr;        // n=0 weight row
    const int bc1 = col0 + 32 + lr;   // n=1 weight row

    f32x16 acc1[2][2], acc2[2][2];
    #pragma unroll
    for (int i = 0; i < 2; ++i)
        #pragma unroll
        for (int j = 0; j < 2; ++j) {
            acc1[i][j] = (f32x16)(0.f);
            acc2[i][j] = (f32x16)(0.f);
        }

    #pragma unroll
    for (int k0 = 0; k0 < Dn; k0 += 16) {
        const int ko = k0 + kh * 8;
        bf16x8 a1[2], a2[2], b1[2], b2[2];
        #pragma unroll
        for (int m = 0; m < 2; ++m) {
            a1[m] = *reinterpret_cast<const bf16x8*>(hB    + (size_t)ar[m] * Dn + ko);
            a2[m] = *reinterpret_cast<const bf16x8*>(selfB + (size_t)ar[m] * Dn + ko);
        }
        b1[0] = *reinterpret_cast<const bf16x8*>(linWb  + (size_t)bc0 * Dn + ko);
        b1[1] = *reinterpret_cast<const bf16x8*>(linWb  + (size_t)bc1 * Dn + ko);
        b2[0] = *reinterpret_cast<const bf16x8*>(skipWb + (size_t)bc0 * Dn + ko);
        b2[1] = *reinterpret_cast<const bf16x8*>(skipWb + (size_t)bc1 * Dn + ko);

        #pragma unroll
        for (int m = 0; m < 2; ++m)
            #pragma unroll
            for (int n = 0; n < 2; ++n) {
                acc1[m][n] = __builtin_amdgcn_mfma_f32_32x32x16_bf16(a1[m], b1[n], acc1[m][n], 0, 0, 0);
                acc2[m][n] = __builtin_amdgcn_mfma_f32_32x32x16_bf16(a2[m], b2[n], acc2[m][n], 0, 0, 0);
            }
    }

    const float beta = beta_p[0];
    const float omb = 1.f - beta;
    #pragma unroll
    for (int n = 0; n < 2; ++n) {
        const int col = col0 + n * 32 + lr;
        const float bias = linb[col];
        #pragma unroll
        for (int m = 0; m < 2; ++m) {
            #pragma unroll
            for (int r = 0; r < 16; ++r) {
                const int row = row0 + m * 32 + (r & 3) + 8 * (r >> 2) + 4 * kh;
                if (row < M) {
                    const float c1 = fmaxf(acc1[m][n][r] + bias, 0.f);
                    enc2b[(size_t)row * Hn + col] = f2bfbits(omb * c1 + beta * acc2[m][n][r]);
                }
            }
        }
    }
}

// ---------------------------------------------------------------------------
// Stage 3 (MFMA): classifier + log_softmax. 64 rows/block, 3 col tiles
// cover 48 padded cols (pad weights zero, pad bias -INF).
// ---------------------------------------------------------------------------
__global__ __launch_bounds__(256) void cls_mfma(
    const unsigned short* __restrict__ enc2b,   // [M,256] bf16
    const unsigned short* __restrict__ clsWb,   // [48,256] bf16 (zero-padded)
    const float* __restrict__ clsb, float* __restrict__ out, int M)
{
    const int w  = threadIdx.x >> 6;
    const int l  = threadIdx.x & 63;
    const int lr = l & 15;
    const int kg = l >> 4;
    const int row0 = blockIdx.x * 64 + w * 16;
    const int arc = (row0 + lr) < M ? (row0 + lr) : (M - 1);

    f32x4 acc[3];
    #pragma unroll
    for (int t = 0; t < 3; ++t) acc[t] = (f32x4){0.f, 0.f, 0.f, 0.f};

    #pragma unroll
    for (int k0 = 0; k0 < Hn; k0 += 32) {
        const int ko = k0 + kg * 8;
        const bf16x8 a = *reinterpret_cast<const bf16x8*>(enc2b + (size_t)arc * Hn + ko);
        #pragma unroll
        for (int t = 0; t < 3; ++t) {
            const bf16x8 bb = *reinterpret_cast<const bf16x8*>(clsWb + (size_t)(t * 16 + lr) * Hn + ko);
            acc[t] = __builtin_amdgcn_mfma_f32_16x16x32_bf16(a, bb, acc[t], 0, 0, 0);
        }
    }

    float bias[3];
    #pragma unroll
    for (int t = 0; t < 3; ++t) {
        const int cb = t * 16 + lr;
        bias[t] = (cb < Cn) ? clsb[cb] : -INFINITY;
    }

    #pragma unroll
    for (int r = 0; r < 4; ++r) {
        float lg0 = acc[0][r] + bias[0];
        float lg1 = acc[1][r] + bias[1];
        float lg2 = acc[2][r] + bias[2];
        float mx = fmaxf(fmaxf(lg0, lg1), lg2);
        #pragma unroll
        for (int off = 8; off; off >>= 1) mx = fmaxf(mx, __shfl_xor(mx, off));
        float se = expf(lg0 - mx) + expf(lg1 - mx) + expf(lg2 - mx);
        #pragma unroll
        for (int off = 8; off; off >>= 1) se += __shfl_xor(se, off);
        const float lse = logf(se);

        const int row = row0 + kg * 4 + r;
        if (row < M) {
            if (lr < 8) out[(size_t)row * Cn + 32 + lr] = lg2 - mx - lse;
            out[(size_t)row * Cn + lr]       = lg0 - mx - lse;
            out[(size_t)row * Cn + 16 + lr]  = lg1 - mx - lse;
        }
    }
}

// ---------------------------------------------------------------------------
// fp32 fallback path (only if ws_size too small for bf16 copies)
// ---------------------------------------------------------------------------
__global__ __launch_bounds__(256) void mp_kernel_f32(
    const int* __restrict__ nodes, const int* __restrict__ structure,
    const float* __restrict__ X, const float* __restrict__ waw_p,
    const float* __restrict__ wab_p, float* __restrict__ h_out, int B)
{
    const int wave = threadIdx.x >> 6;
    const int lane = threadIdx.x & 63;
    const int b = blockIdx.x * 4 + wave;
    if (b >= B) return;
    const int ub = __builtin_amdgcn_readfirstlane(b);

    const float waw = waw_p[0];
    const float wab = wab_p[0];
    const float4* __restrict__ Xv = reinterpret_cast<const float4*>(X);

    float4 neigh = make_float4(0.f, 0.f, 0.f, 0.f);
    const int* st = structure + (size_t)ub * (En * Kn);

    #pragma unroll 1
    for (int e = 0; e < En; ++e) {
        const int i0 = st[e * 3 + 0];
        const int i1 = st[e * 3 + 1];
        const int i2 = st[e * 3 + 2];
        const float4 f0 = Xv[(size_t)i0 * (Dn / 4) + lane];
        const float4 f1 = Xv[(size_t)i1 * (Dn / 4) + lane];
        const float4 f2 = Xv[(size_t)i2 * (Dn / 4) + lane];
        float pv = 0.f;
        {
            float a, bb, c, m;
            a = f0.x; bb = f1.x; c = f2.x;
            m = (a + bb + c) * (1.f / 3.f);
            pv += (a * a + bb * bb + c * c) * (1.f / 3.f) - m * m;
            a = f0.y; bb = f1.y; c = f2.y;
            m = (a + bb + c) * (1.f / 3.f);
            pv += (a * a + bb * bb + c * c) * (1.f / 3.f) - m * m;
            a = f0.z; bb = f1.z; c = f2.z;
            m = (a + bb + c) * (1.f / 3.f);
            pv += (a * a + bb * bb + c * c) * (1.f / 3.f) - m * m;
            a = f0.w; bb = f1.w; c = f2.w;
            m = (a + bb + c) * (1.f / 3.f);
            pv += (a * a + bb * bb + c * c) * (1.f / 3.f) - m * m;
        }
        #pragma unroll
        for (int off = 32; off; off >>= 1) pv += __shfl_xor(pv, off);
        const float var_mean = pv * (1.f / (float)Dn);
        const float att = 1.f / (1.f + expf(-(waw * var_mean + wab)));
        neigh.x += att * f0.x * f1.x;
        neigh.y += att * f0.y * f1.y;
        neigh.z += att * f0.z * f1.z;
        neigh.w += att * f0.w * f1.w;
    }

    const float4 s = Xv[(size_t)nodes[ub] * (Dn / 4) + lane];
    float4 h;
    h.x = s.x + neigh.x; h.y = s.y + neigh.y;
    h.z = s.z + neigh.z; h.w = s.w + neigh.w;
    reinterpret_cast<float4*>(h_out)[(size_t)b * (Dn / 4) + lane] = h;
}

#define BM 64
#define BN 64
#define BKs 16
#define LDT 68

__global__ __launch_bounds__(256) void enc_gemm_f32(
    const float* __restrict__ hA, const int* __restrict__ nodes,
    const float* __restrict__ X,
    const float* __restrict__ linW, const float* __restrict__ linb,
    const float* __restrict__ skipW, const float* __restrict__ beta_p,
    float* __restrict__ enc2, int M)
{
    __shared__ float Ats1[BKs][LDT];
    __shared__ float Ats2[BKs][LDT];
    __shared__ float Bts1[BKs][LDT];
    __shared__ float Bts2[BKs][LDT];

    const int tid = threadIdx.x;
    const int tx = tid & 15;
    const int ty = tid >> 4;
    const int row0 = blockIdx.x * BM;
    const int col0 = blockIdx.y * BN;

    const int lr = tid >> 2;
    const int lc = tid & 3;

    const int arow = row0 + lr;
    const bool arow_ok = arow < M;
    const int self_row = arow_ok ? nodes[arow] : 0;

    float acc1[4][4] = {{0.f}}, acc2[4][4] = {{0.f}};

    for (int k0 = 0; k0 < Dn; k0 += BKs) {
        float4 a1v = make_float4(0.f, 0.f, 0.f, 0.f);
        float4 a2v = make_float4(0.f, 0.f, 0.f, 0.f);
        if (arow_ok) {
            a1v = *reinterpret_cast<const float4*>(hA + (size_t)arow * Dn + k0 + lc * 4);
            a2v = *reinterpret_cast<const float4*>(X + (size_t)self_row * Dn + k0 + lc * 4);
        }
        const float4 b1v = *reinterpret_cast<const float4*>(linW + (size_t)(col0 + lr) * Dn + k0 + lc * 4);
        const float4 b2v = *reinterpret_cast<const float4*>(skipW + (size_t)(col0 + lr) * Dn + k0 + lc * 4);

        __syncthreads();
        Ats1[lc * 4 + 0][lr] = a1v.x; Ats1[lc * 4 + 1][lr] = a1v.y;
        Ats1[lc * 4 + 2][lr] = a1v.z; Ats1[lc * 4 + 3][lr] = a1v.w;
        Ats2[lc * 4 + 0][lr] = a2v.x; Ats2[lc * 4 + 1][lr] = a2v.y;
        Ats2[lc * 4 + 2][lr] = a2v.z; Ats2[lc * 4 + 3][lr] = a2v.w;
        Bts1[lc * 4 + 0][lr] = b1v.x; Bts1[lc * 4 + 1][lr] = b1v.y;
        Bts1[lc * 4 + 2][lr] = b1v.z; Bts1[lc * 4 + 3][lr] = b1v.w;
        Bts2[lc * 4 + 0][lr] = b2v.x; Bts2[lc * 4 + 1][lr] = b2v.y;
        Bts2[lc * 4 + 2][lr] = b2v.z; Bts2[lc * 4 + 3][lr] = b2v.w;
        __syncthreads();

        #pragma unroll
        for (int kk = 0; kk < BKs; ++kk) {
            const float4 a1 = *reinterpret_cast<const float4*>(&Ats1[kk][ty * 4]);
            const float4 a2 = *reinterpret_cast<const float4*>(&Ats2[kk][ty * 4]);
            const float4 b1 = *reinterpret_cast<const float4*>(&Bts1[kk][tx * 4]);
            const float4 b2 = *reinterpret_cast<const float4*>(&Bts2[kk][tx * 4]);
            const float a1a[4] = {a1.x, a1.y, a1.z, a1.w};
            const float a2a[4] = {a2.x, a2.y, a2.z, a2.w};
            const float b1a[4] = {b1.x, b1.y, b1.z, b1.w};
            const float b2a[4] = {b2.x, b2.y, b2.z, b2.w};
            #pragma unroll
            for (int i = 0; i < 4; ++i)
                #pragma unroll
                for (int j = 0; j < 4; ++j) {
                    acc1[i][j] = fmaf(a1a[i], b1a[j], acc1[i][j]);
                    acc2[i][j] = fmaf(a2a[i], b2a[j], acc2[i][j]);
                }
        }
    }

    const float beta = beta_p[0];
    const float omb = 1.f - beta;
    #pragma unroll
    for (int i = 0; i < 4; ++i) {
        const int r = row0 + ty * 4 + i;
        if (r >= M) continue;
        #pragma unroll
        for (int j = 0; j < 4; ++j) {
            const int c = col0 + tx * 4 + j;
            float c1 = acc1[i][j] + linb[c];
            c1 = fmaxf(c1, 0.f);
            enc2[(size_t)r * Hn + c] = omb * c1 + beta * acc2[i][j];
        }
    }
}

__global__ __launch_bounds__(256) void cls_kernel_f32(
    const float* __restrict__ enc2, const float* __restrict__ clsW,
    const float* __restrict__ clsb, float* __restrict__ out, int B)
{
    const int wave = threadIdx.x >> 6;
    const int lane = threadIdx.x & 63;
    const int b = blockIdx.x * 4 + wave;
    if (b >= B) return;

    const float4 e = reinterpret_cast<const float4*>(enc2 + (size_t)b * Hn)[lane];
    const float4* __restrict__ clsWv = reinterpret_cast<const float4*>(clsW);

    float mylogit = -INFINITY;
    #pragma unroll
    for (int c0 = 0; c0 < Cn; c0 += 8) {
        float p[8];
        #pragma unroll
        for (int u = 0; u < 8; ++u) {
            const float4 wv = clsWv[(size_t)(c0 + u) * (Hn / 4) + lane];
            p[u] = e.x * wv.x + e.y * wv.y + e.z * wv.z + e.w * wv.w;
        }
        #pragma unroll
        for (int off = 32; off; off >>= 1) {
            #pragma unroll
            for (int u = 0; u < 8; ++u) p[u] += __shfl_xor(p[u], off);
        }
        #pragma unroll
        for (int u = 0; u < 8; ++u)
            if (lane == c0 + u) mylogit = p[u];
    }
    if (lane < Cn) mylogit += clsb[lane];

    float mx = mylogit;
    #pragma unroll
    for (int off = 32; off; off >>= 1) mx = fmaxf(mx, __shfl_xor(mx, off));
    float ex = (lane < Cn) ? expf(mylogit - mx) : 0.f;
    float se = ex;
    #pragma unroll
    for (int off = 32; off; off >>= 1) se += __shfl_xor(se, off);
    const float lse = logf(se);

    if (lane < Cn) out[(size_t)b * Cn + lane] = mylogit - mx - lse;
}

// ---------------------------------------------------------------------------
extern "C" void kernel_launch(void* const* d_in, const int* in_sizes, int n_in,
                              void* d_out, int out_size, void* d_ws, size_t ws_size,
                              hipStream_t stream) {
    const int*   nodes     = (const int*)d_in[0];
    const int*   structure = (const int*)d_in[1];
    const float* X         = (const float*)d_in[2];
    const float* beta      = (const float*)d_in[3];
    const float* waw       = (const float*)d_in[4];
    const float* wab       = (const float*)d_in[5];
    const float* linW      = (const float*)d_in[6];
    const float* linb      = (const float*)d_in[7];
    const float* skipW     = (const float*)d_in[8];
    const float* clsW      = (const float*)d_in[9];
    const float* clsb      = (const float*)d_in[10];
    float* out = (float*)d_out;

    const int B = in_sizes[0];
    const int Ntot = in_sizes[2];            // N * D floats

    // ws layout (bf16 path):
    //   enc2b  [B,H]   bf16
    //   h_bf   [B,D]   bf16
    //   selfb  [B,D]   bf16
    //   Xb     [N,D]   bf16
    //   linWb  [H,D]   bf16
    //   skipWb [H,D]   bf16
    //   clsWb  [48,H]  bf16 (zero-padded)
    unsigned short* enc2b  = (unsigned short*)d_ws;
    unsigned short* h_bf   = enc2b + (size_t)B * Hn;
    unsigned short* selfb  = h_bf + (size_t)B * Dn;
    unsigned short* Xb     = selfb + (size_t)B * Dn;
    unsigned short* linWb  = Xb + (size_t)Ntot;
    unsigned short* skipWb = linWb + (size_t)Hn * Dn;
    unsigned short* clsWb  = skipWb + (size_t)Hn * Dn;

    const size_t need = ((size_t)B * Hn + (size_t)B * Dn * 2 + (size_t)Ntot +
                         (size_t)Hn * Dn * 2 + (size_t)CnP * Hn) * 2;

    if (ws_size >= need) {
        // Stage 0: one merged bf16 conversion launch
        const int x8 = Ntot / 8;
        const int w8 = (Hn * Dn) / 8;
        const int c8 = (CnP * Hn) / 8;
        const int G = x8 + 2 * w8 + c8;
        conv_all<<<(G + 255) / 256, 256, 0, stream>>>(
            X, linW, skipW, clsW,
            (uint4*)Xb, (uint4*)linWb, (uint4*)skipWb, (uint4*)clsWb, x8, w8);

        // Stage 1: message passing (bf16 gathers) -> h_bf, selfb
        mp_kernel_bf<<<(B + 3) / 4, 256, 0, stream>>>(
            nodes, structure, (const uint2*)Xb, waw, wab,
            (uint2*)h_bf, (uint2*)selfb, B);

        // Stage 2: MFMA 32x32 dual GEMM -> enc2b (bf16)
        dim3 g2((B + 127) / 128, Hn / 128);
        enc_gemm_mfma32<<<g2, 256, 0, stream>>>(
            h_bf, selfb, linWb, linb, skipWb, beta, enc2b, B);

        // Stage 3: MFMA classifier + log_softmax -> out
        cls_mfma<<<(B + 63) / 64, 256, 0, stream>>>(enc2b, clsWb, clsb, out, B);
    } else {
        float* enc2 = (float*)d_ws;
        float* hf   = enc2 + (size_t)B * Hn;
        mp_kernel_f32<<<(B + 3) / 4, 256, 0, stream>>>(nodes, structure, X, waw, wab, hf, B);
        dim3 g2((B + BM - 1) / BM, Hn / BN);
        enc_gemm_f32<<<g2, 256, 0, stream>>>(hf, nodes, X, linW, linb, skipW, beta, enc2, B);
        cls_kernel_f32<<<(B + 3) / 4, 256, 0, stream>>>(enc2, clsW, clsb, out, B);
    }
}

// Round 8
// 138.355 us; speedup vs baseline: 2.0349x; 1.0909x over previous
//
#include <hip/hip_runtime.h>
#include <hip/hip_bf16.h>
#include <math.h>

// Problem constants (from reference)
#define Dn 256     // feature dim
#define En 16      // hyperedges per node
#define Kn 3       // nodes per hyperedge
#define Hn 256     // hidden dim
#define Cn 40      // classes
#define CnP 48     // classes padded to 3x16 for MFMA col tiles

typedef __attribute__((ext_vector_type(8)))  short bf16x8;
typedef __attribute__((ext_vector_type(4)))  float f32x4;
typedef __attribute__((ext_vector_type(16))) float f32x16;

static __device__ __forceinline__ float bf2f(unsigned short u) {
    return __uint_as_float(((unsigned)u) << 16);
}
static __device__ __forceinline__ unsigned short f2bfbits(float v) {
    __hip_bfloat16 hb = __float2bfloat16(v);
    return *reinterpret_cast<unsigned short*>(&hb);
}
static __device__ __forceinline__ unsigned pack2bf(float a, float b) {
    return (unsigned)f2bfbits(a) | ((unsigned)f2bfbits(b) << 16);
}
// LDS swizzle: rows are 512B; XOR row&7 into byte bits 4..6 (16B slots).
static __device__ __forceinline__ unsigned swz(unsigned boff) {
    return boff ^ (((boff >> 9) & 7u) << 4);
}

// ---------------------------------------------------------------------------
// Stage 0: merged fp32 -> bf16 conversion: X, lin_W, skip_W, cls_W (padded
// to 48 rows with zeros). One launch; each thread converts 8 floats.
// ---------------------------------------------------------------------------
__global__ __launch_bounds__(256) void conv_all(
    const float* __restrict__ X, const float* __restrict__ linW,
    const float* __restrict__ skipW, const float* __restrict__ clsW,
    uint4* __restrict__ Xb, uint4* __restrict__ linWb,
    uint4* __restrict__ skipWb, uint4* __restrict__ clsWb,
    int x8, int w8)
{
    int t = blockIdx.x * 256 + threadIdx.x;
    const int c8 = (CnP * Hn) / 8;
    if (t < x8) {
        const float4* iv = reinterpret_cast<const float4*>(X);
        const float4 a = iv[(size_t)t * 2 + 0];
        const float4 b = iv[(size_t)t * 2 + 1];
        Xb[t] = (uint4){pack2bf(a.x, a.y), pack2bf(a.z, a.w),
                        pack2bf(b.x, b.y), pack2bf(b.z, b.w)};
        return;
    }
    t -= x8;
    if (t < w8) {
        const float4* iv = reinterpret_cast<const float4*>(linW);
        const float4 a = iv[(size_t)t * 2 + 0];
        const float4 b = iv[(size_t)t * 2 + 1];
        linWb[t] = (uint4){pack2bf(a.x, a.y), pack2bf(a.z, a.w),
                           pack2bf(b.x, b.y), pack2bf(b.z, b.w)};
        return;
    }
    t -= w8;
    if (t < w8) {
        const float4* iv = reinterpret_cast<const float4*>(skipW);
        const float4 a = iv[(size_t)t * 2 + 0];
        const float4 b = iv[(size_t)t * 2 + 1];
        skipWb[t] = (uint4){pack2bf(a.x, a.y), pack2bf(a.z, a.w),
                            pack2bf(b.x, b.y), pack2bf(b.z, b.w)};
        return;
    }
    t -= w8;
    if (t < c8) {
        const int row = t >> 5;               // 32 groups of 8 per 256-col row
        if (row < Cn) {
            const float4* iv = reinterpret_cast<const float4*>(clsW);
            const float4 a = iv[(size_t)t * 2 + 0];
            const float4 b = iv[(size_t)t * 2 + 1];
            clsWb[t] = (uint4){pack2bf(a.x, a.y), pack2bf(a.z, a.w),
                               pack2bf(b.x, b.y), pack2bf(b.z, b.w)};
        } else {
            clsWb[t] = (uint4){0u, 0u, 0u, 0u};
        }
    }
}

// ---------------------------------------------------------------------------
// Stage 1 (bf16): message passing. One wave per node b; lane owns 4 dims.
// Variance via S2-C identity: sum_d var_d = 2*(S2 - C)/9.
// Streams the self row out (selfb) so the GEMM reads it contiguously.
// ---------------------------------------------------------------------------
__global__ __launch_bounds__(256) void mp_kernel_bf(
    const int* __restrict__ nodes, const int* __restrict__ structure,
    const uint2* __restrict__ Xb,
    const float* __restrict__ waw_p, const float* __restrict__ wab_p,
    uint2* __restrict__ h_out, uint2* __restrict__ self_out, int B)
{
    const int wave = threadIdx.x >> 6;
    const int lane = threadIdx.x & 63;
    const int b = blockIdx.x * 4 + wave;
    if (b >= B) return;
    const int ub = __builtin_amdgcn_readfirstlane(b);  // wave-uniform

    const float waw = waw_p[0];
    const float wab = wab_p[0];

    float4 neigh = make_float4(0.f, 0.f, 0.f, 0.f);
    const int* st = structure + (size_t)ub * (En * Kn);

    #pragma unroll 1
    for (int g = 0; g < En / 4; ++g) {
        int idx[12];
        #pragma unroll
        for (int u = 0; u < 12; ++u) idx[u] = st[g * 12 + u];

        uint2 r0[4], r1[4], r2[4];
        #pragma unroll
        for (int u = 0; u < 4; ++u) {
            r0[u] = Xb[(size_t)idx[u * 3 + 0] * (Dn / 4) + lane];
            r1[u] = Xb[(size_t)idx[u * 3 + 1] * (Dn / 4) + lane];
            r2[u] = Xb[(size_t)idx[u * 3 + 2] * (Dn / 4) + lane];
        }

        float pv[4];
        float4 msg[4];
        #pragma unroll
        for (int u = 0; u < 4; ++u) {
            float4 f0, f1, f2;
            f0.x = bf2f((unsigned short)(r0[u].x & 0xffff));
            f0.y = bf2f((unsigned short)(r0[u].x >> 16));
            f0.z = bf2f((unsigned short)(r0[u].y & 0xffff));
            f0.w = bf2f((unsigned short)(r0[u].y >> 16));
            f1.x = bf2f((unsigned short)(r1[u].x & 0xffff));
            f1.y = bf2f((unsigned short)(r1[u].x >> 16));
            f1.z = bf2f((unsigned short)(r1[u].y & 0xffff));
            f1.w = bf2f((unsigned short)(r1[u].y >> 16));
            f2.x = bf2f((unsigned short)(r2[u].x & 0xffff));
            f2.y = bf2f((unsigned short)(r2[u].x >> 16));
            f2.z = bf2f((unsigned short)(r2[u].y & 0xffff));
            f2.w = bf2f((unsigned short)(r2[u].y >> 16));

            float s2 = 0.f, cr = 0.f, tt;
            s2 = fmaf(f0.x, f0.x, s2); s2 = fmaf(f1.x, f1.x, s2); s2 = fmaf(f2.x, f2.x, s2);
            tt = f1.x + f2.x; cr = fmaf(f0.x, tt, cr); cr = fmaf(f1.x, f2.x, cr);
            s2 = fmaf(f0.y, f0.y, s2); s2 = fmaf(f1.y, f1.y, s2); s2 = fmaf(f2.y, f2.y, s2);
            tt = f1.y + f2.y; cr = fmaf(f0.y, tt, cr); cr = fmaf(f1.y, f2.y, cr);
            s2 = fmaf(f0.z, f0.z, s2); s2 = fmaf(f1.z, f1.z, s2); s2 = fmaf(f2.z, f2.z, s2);
            tt = f1.z + f2.z; cr = fmaf(f0.z, tt, cr); cr = fmaf(f1.z, f2.z, cr);
            s2 = fmaf(f0.w, f0.w, s2); s2 = fmaf(f1.w, f1.w, s2); s2 = fmaf(f2.w, f2.w, s2);
            tt = f1.w + f2.w; cr = fmaf(f0.w, tt, cr); cr = fmaf(f1.w, f2.w, cr);

            pv[u] = s2 - cr;
            msg[u].x = f0.x * f1.x;
            msg[u].y = f0.y * f1.y;
            msg[u].z = f0.z * f1.z;
            msg[u].w = f0.w * f1.w;
        }

        #pragma unroll
        for (int off = 32; off; off >>= 1) {
            #pragma unroll
            for (int u = 0; u < 4; ++u) pv[u] += __shfl_xor(pv[u], off);
        }

        #pragma unroll
        for (int u = 0; u < 4; ++u) {
            const float var_mean = pv[u] * (2.f / (9.f * (float)Dn));
            const float att = 1.f / (1.f + expf(-(waw * var_mean + wab)));
            neigh.x += att * msg[u].x;
            neigh.y += att * msg[u].y;
            neigh.z += att * msg[u].z;
            neigh.w += att * msg[u].w;
        }
    }

    const uint2 sv = Xb[(size_t)nodes[ub] * (Dn / 4) + lane];
    self_out[(size_t)b * (Dn / 4) + lane] = sv;
    const float sx = bf2f((unsigned short)(sv.x & 0xffff));
    const float sy = bf2f((unsigned short)(sv.x >> 16));
    const float sz = bf2f((unsigned short)(sv.y & 0xffff));
    const float sw = bf2f((unsigned short)(sv.y >> 16));
    uint2 o;
    o.x = pack2bf(sx + neigh.x, sy + neigh.y);
    o.y = pack2bf(sz + neigh.z, sw + neigh.w);
    h_out[(size_t)b * (Dn / 4) + lane] = o;
}

// ---------------------------------------------------------------------------
// Stage 2+3 FUSED: dual GEMM (32x32x16 MFMA) -> LDS -> classifier (16x16x32)
// -> log_softmax -> out. Block = 32 rows x 256 cols, 4 waves (wave w owns
// cols [w*64, w*64+64)). enc tile staged in XOR-swizzled LDS (16KB); waves
// 0,1 then each compute cls for 16 rows. Grid ~626 blocks (=2.4/CU balance).
// MFMA layouts (gfx950, verified): 32x32: A row=lane&31, k=(lane>>5)*8+i;
// D col=lane&31, row=(r&3)+8*(r>>2)+4*(lane>>5). 16x16: A row=lane&15,
// k=(lane>>4)*8+i; D col=lane&15, row=(lane>>4)*4+r.
// ---------------------------------------------------------------------------
__global__ __launch_bounds__(256, 2) void enc_cls_fused(
    const unsigned short* __restrict__ hB,     // [M,256] bf16
    const unsigned short* __restrict__ selfB,  // [M,256] bf16
    const unsigned short* __restrict__ linWb, const float* __restrict__ linb,
    const unsigned short* __restrict__ skipWb, const float* __restrict__ beta_p,
    const unsigned short* __restrict__ clsWb,  // [48,256] bf16 zero-padded
    const float* __restrict__ clsb,
    float* __restrict__ out, int M)
{
    __shared__ unsigned short elds[32 * 256];  // 16 KB, swizzled

    const int w  = threadIdx.x >> 6;   // col panel 0..3
    const int l  = threadIdx.x & 63;
    const int lr = l & 31;
    const int kh = l >> 5;
    const int row0 = blockIdx.x * 32;

    const int arow = row0 + lr;
    const int arc  = arow < M ? arow : (M - 1);
    const int bc0 = w * 64 + lr;
    const int bc1 = w * 64 + 32 + lr;

    f32x16 acc1[2], acc2[2];   // [n]: cols n*32 within panel
    acc1[0] = (f32x16)(0.f); acc1[1] = (f32x16)(0.f);
    acc2[0] = (f32x16)(0.f); acc2[1] = (f32x16)(0.f);

    #pragma unroll 4
    for (int k0 = 0; k0 < Dn; k0 += 16) {
        const int ko = k0 + kh * 8;
        const bf16x8 a1  = *reinterpret_cast<const bf16x8*>(hB    + (size_t)arc * Dn + ko);
        const bf16x8 a2  = *reinterpret_cast<const bf16x8*>(selfB + (size_t)arc * Dn + ko);
        const bf16x8 b10 = *reinterpret_cast<const bf16x8*>(linWb  + (size_t)bc0 * Dn + ko);
        const bf16x8 b11 = *reinterpret_cast<const bf16x8*>(linWb  + (size_t)bc1 * Dn + ko);
        const bf16x8 b20 = *reinterpret_cast<const bf16x8*>(skipWb + (size_t)bc0 * Dn + ko);
        const bf16x8 b21 = *reinterpret_cast<const bf16x8*>(skipWb + (size_t)bc1 * Dn + ko);
        acc1[0] = __builtin_amdgcn_mfma_f32_32x32x16_bf16(a1, b10, acc1[0], 0, 0, 0);
        acc1[1] = __builtin_amdgcn_mfma_f32_32x32x16_bf16(a1, b11, acc1[1], 0, 0, 0);
        acc2[0] = __builtin_amdgcn_mfma_f32_32x32x16_bf16(a2, b20, acc2[0], 0, 0, 0);
        acc2[1] = __builtin_amdgcn_mfma_f32_32x32x16_bf16(a2, b21, acc2[1], 0, 0, 0);
    }

    // epilogue: enc value -> swizzled LDS (bf16)
    const float beta = beta_p[0];
    const float omb = 1.f - beta;
    #pragma unroll
    for (int n = 0; n < 2; ++n) {
        const int col = w * 64 + n * 32 + lr;
        const float bias = linb[col];
        #pragma unroll
        for (int r = 0; r < 16; ++r) {
            const int rowl = (r & 3) + 8 * (r >> 2) + 4 * kh;   // 0..31
            const float c1 = fmaxf(acc1[n][r] + bias, 0.f);
            const unsigned short v = f2bfbits(omb * c1 + beta * acc2[n][r]);
            const unsigned boff = swz((unsigned)(rowl * 512 + col * 2));
            *reinterpret_cast<unsigned short*>(
                reinterpret_cast<char*>(elds) + boff) = v;
        }
    }
    __syncthreads();

    // cls phase: waves 0,1 each handle 16 rows
    if (w < 2) {
        const int lr16 = l & 15;
        const int kg = l >> 4;
        const int rowl0 = w * 16 + lr16;

        f32x4 cacc[3];
        cacc[0] = (f32x4){0.f,0.f,0.f,0.f};
        cacc[1] = (f32x4){0.f,0.f,0.f,0.f};
        cacc[2] = (f32x4){0.f,0.f,0.f,0.f};

        #pragma unroll
        for (int k0 = 0; k0 < Hn; k0 += 32) {
            const int ko = k0 + kg * 8;
            const unsigned boff = swz((unsigned)(rowl0 * 512 + ko * 2));
            const bf16x8 a = *reinterpret_cast<const bf16x8*>(
                reinterpret_cast<const char*>(elds) + boff);
            #pragma unroll
            for (int t = 0; t < 3; ++t) {
                const bf16x8 bb = *reinterpret_cast<const bf16x8*>(
                    clsWb + (size_t)(t * 16 + lr16) * Hn + ko);
                cacc[t] = __builtin_amdgcn_mfma_f32_16x16x32_bf16(a, bb, cacc[t], 0, 0, 0);
            }
        }

        float bias3[3];
        #pragma unroll
        for (int t = 0; t < 3; ++t) {
            const int cb = t * 16 + lr16;
            bias3[t] = (cb < Cn) ? clsb[cb] : -INFINITY;
        }

        #pragma unroll
        for (int r = 0; r < 4; ++r) {
            float lg0 = cacc[0][r] + bias3[0];
            float lg1 = cacc[1][r] + bias3[1];
            float lg2 = cacc[2][r] + bias3[2];
            float mx = fmaxf(fmaxf(lg0, lg1), lg2);
            #pragma unroll
            for (int off = 8; off; off >>= 1) mx = fmaxf(mx, __shfl_xor(mx, off));
            float se = expf(lg0 - mx) + expf(lg1 - mx) + expf(lg2 - mx);
            #pragma unroll
            for (int off = 8; off; off >>= 1) se += __shfl_xor(se, off);
            const float lse = logf(se);

            const int row = row0 + w * 16 + kg * 4 + r;
            if (row < M) {
                if (lr16 < 8) out[(size_t)row * Cn + 32 + lr16] = lg2 - mx - lse;
                out[(size_t)row * Cn + lr16]      = lg0 - mx - lse;
                out[(size_t)row * Cn + 16 + lr16] = lg1 - mx - lse;
            }
        }
    }
}

// ---------------------------------------------------------------------------
// fp32 fallback path (only if ws_size too small for bf16 copies)
// ---------------------------------------------------------------------------
__global__ __launch_bounds__(256) void mp_kernel_f32(
    const int* __restrict__ nodes, const int* __restrict__ structure,
    const float* __restrict__ X, const float* __restrict__ waw_p,
    const float* __restrict__ wab_p, float* __restrict__ h_out, int B)
{
    const int wave = threadIdx.x >> 6;
    const int lane = threadIdx.x & 63;
    const int b = blockIdx.x * 4 + wave;
    if (b >= B) return;
    const int ub = __builtin_amdgcn_readfirstlane(b);

    const float waw = waw_p[0];
    const float wab = wab_p[0];
    const float4* __restrict__ Xv = reinterpret_cast<const float4*>(X);

    float4 neigh = make_float4(0.f, 0.f, 0.f, 0.f);
    const int* st = structure + (size_t)ub * (En * Kn);

    #pragma unroll 1
    for (int e = 0; e < En; ++e) {
        const int i0 = st[e * 3 + 0];
        const int i1 = st[e * 3 + 1];
        const int i2 = st[e * 3 + 2];
        const float4 f0 = Xv[(size_t)i0 * (Dn / 4) + lane];
        const float4 f1 = Xv[(size_t)i1 * (Dn / 4) + lane];
        const float4 f2 = Xv[(size_t)i2 * (Dn / 4) + lane];
        float pv = 0.f;
        {
            float a, bb, c, m;
            a = f0.x; bb = f1.x; c = f2.x;
            m = (a + bb + c) * (1.f / 3.f);
            pv += (a * a + bb * bb + c * c) * (1.f / 3.f) - m * m;
            a = f0.y; bb = f1.y; c = f2.y;
            m = (a + bb + c) * (1.f / 3.f);
            pv += (a * a + bb * bb + c * c) * (1.f / 3.f) - m * m;
            a = f0.z; bb = f1.z; c = f2.z;
            m = (a + bb + c) * (1.f / 3.f);
            pv += (a * a + bb * bb + c * c) * (1.f / 3.f) - m * m;
            a = f0.w; bb = f1.w; c = f2.w;
            m = (a + bb + c) * (1.f / 3.f);
            pv += (a * a + bb * bb + c * c) * (1.f / 3.f) - m * m;
        }
        #pragma unroll
        for (int off = 32; off; off >>= 1) pv += __shfl_xor(pv, off);
        const float var_mean = pv * (1.f / (float)Dn);
        const float att = 1.f / (1.f + expf(-(waw * var_mean + wab)));
        neigh.x += att * f0.x * f1.x;
        neigh.y += att * f0.y * f1.y;
        neigh.z += att * f0.z * f1.z;
        neigh.w += att * f0.w * f1.w;
    }

    const float4 s = Xv[(size_t)nodes[ub] * (Dn / 4) + lane];
    float4 h;
    h.x = s.x + neigh.x; h.y = s.y + neigh.y;
    h.z = s.z + neigh.z; h.w = s.w + neigh.w;
    reinterpret_cast<float4*>(h_out)[(size_t)b * (Dn / 4) + lane] = h;
}

#define BM 64
#define BN 64
#define BKs 16
#define LDT 68

__global__ __launch_bounds__(256) void enc_gemm_f32(
    const float* __restrict__ hA, const int* __restrict__ nodes,
    const float* __restrict__ X,
    const float* __restrict__ linW, const float* __restrict__ linb,
    const float* __restrict__ skipW, const float* __restrict__ beta_p,
    float* __restrict__ enc2, int M)
{
    __shared__ float Ats1[BKs][LDT];
    __shared__ float Ats2[BKs][LDT];
    __shared__ float Bts1[BKs][LDT];
    __shared__ float Bts2[BKs][LDT];

    const int tid = threadIdx.x;
    const int tx = tid & 15;
    const int ty = tid >> 4;
    const int row0 = blockIdx.x * BM;
    const int col0 = blockIdx.y * BN;

    const int lr = tid >> 2;
    const int lc = tid & 3;

    const int arow = row0 + lr;
    const bool arow_ok = arow < M;
    const int self_row = arow_ok ? nodes[arow] : 0;

    float acc1[4][4] = {{0.f}}, acc2[4][4] = {{0.f}};

    for (int k0 = 0; k0 < Dn; k0 += BKs) {
        float4 a1v = make_float4(0.f, 0.f, 0.f, 0.f);
        float4 a2v = make_float4(0.f, 0.f, 0.f, 0.f);
        if (arow_ok) {
            a1v = *reinterpret_cast<const float4*>(hA + (size_t)arow * Dn + k0 + lc * 4);
            a2v = *reinterpret_cast<const float4*>(X + (size_t)self_row * Dn + k0 + lc * 4);
        }
        const float4 b1v = *reinterpret_cast<const float4*>(linW + (size_t)(col0 + lr) * Dn + k0 + lc * 4);
        const float4 b2v = *reinterpret_cast<const float4*>(skipW + (size_t)(col0 + lr) * Dn + k0 + lc * 4);

        __syncthreads();
        Ats1[lc * 4 + 0][lr] = a1v.x; Ats1[lc * 4 + 1][lr] = a1v.y;
        Ats1[lc * 4 + 2][lr] = a1v.z; Ats1[lc * 4 + 3][lr] = a1v.w;
        Ats2[lc * 4 + 0][lr] = a2v.x; Ats2[lc * 4 + 1][lr] = a2v.y;
        Ats2[lc * 4 + 2][lr] = a2v.z; Ats2[lc * 4 + 3][lr] = a2v.w;
        Bts1[lc * 4 + 0][lr] = b1v.x; Bts1[lc * 4 + 1][lr] = b1v.y;
        Bts1[lc * 4 + 2][lr] = b1v.z; Bts1[lc * 4 + 3][lr] = b1v.w;
        Bts2[lc * 4 + 0][lr] = b2v.x; Bts2[lc * 4 + 1][lr] = b2v.y;
        Bts2[lc * 4 + 2][lr] = b2v.z; Bts2[lc * 4 + 3][lr] = b2v.w;
        __syncthreads();

        #pragma unroll
        for (int kk = 0; kk < BKs; ++kk) {
            const float4 a1 = *reinterpret_cast<const float4*>(&Ats1[kk][ty * 4]);
            const float4 a2 = *reinterpret_cast<const float4*>(&Ats2[kk][ty * 4]);
            const float4 b1 = *reinterpret_cast<const float4*>(&Bts1[kk][tx * 4]);
            const float4 b2 = *reinterpret_cast<const float4*>(&Bts2[kk][tx * 4]);
            const float a1a[4] = {a1.x, a1.y, a1.z, a1.w};
            const float a2a[4] = {a2.x, a2.y, a2.z, a2.w};
            const float b1a[4] = {b1.x, b1.y, b1.z, b1.w};
            const float b2a[4] = {b2.x, b2.y, b2.z, b2.w};
            #pragma unroll
            for (int i = 0; i < 4; ++i)
                #pragma unroll
                for (int j = 0; j < 4; ++j) {
                    acc1[i][j] = fmaf(a1a[i], b1a[j], acc1[i][j]);
                    acc2[i][j] = fmaf(a2a[i], b2a[j], acc2[i][j]);
                }
        }
    }

    const float beta = beta_p[0];
    const float omb = 1.f - beta;
    #pragma unroll
    for (int i = 0; i < 4; ++i) {
        const int r = row0 + ty * 4 + i;
        if (r >= M) continue;
        #pragma unroll
        for (int j = 0; j < 4; ++j) {
            const int c = col0 + tx * 4 + j;
            float c1 = acc1[i][j] + linb[c];
            c1 = fmaxf(c1, 0.f);
            enc2[(size_t)r * Hn + c] = omb * c1 + beta * acc2[i][j];
        }
    }
}

__global__ __launch_bounds__(256) void cls_kernel_f32(
    const float* __restrict__ enc2, const float* __restrict__ clsW,
    const float* __restrict__ clsb, float* __restrict__ out, int B)
{
    const int wave = threadIdx.x >> 6;
    const int lane = threadIdx.x & 63;
    const int b = blockIdx.x * 4 + wave;
    if (b >= B) return;

    const float4 e = reinterpret_cast<const float4*>(enc2 + (size_t)b * Hn)[lane];
    const float4* __restrict__ clsWv = reinterpret_cast<const float4*>(clsW);

    float mylogit = -INFINITY;
    #pragma unroll
    for (int c0 = 0; c0 < Cn; c0 += 8) {
        float p[8];
        #pragma unroll
        for (int u = 0; u < 8; ++u) {
            const float4 wv = clsWv[(size_t)(c0 + u) * (Hn / 4) + lane];
            p[u] = e.x * wv.x + e.y * wv.y + e.z * wv.z + e.w * wv.w;
        }
        #pragma unroll
        for (int off = 32; off; off >>= 1) {
            #pragma unroll
            for (int u = 0; u < 8; ++u) p[u] += __shfl_xor(p[u], off);
        }
        #pragma unroll
        for (int u = 0; u < 8; ++u)
            if (lane == c0 + u) mylogit = p[u];
    }
    if (lane < Cn) mylogit += clsb[lane];

    float mx = mylogit;
    #pragma unroll
    for (int off = 32; off; off >>= 1) mx = fmaxf(mx, __shfl_xor(mx, off));
    float ex = (lane < Cn) ? expf(mylogit - mx) : 0.f;
    float se = ex;
    #pragma unroll
    for (int off = 32; off; off >>= 1) se += __shfl_xor(se, off);
    const float lse = logf(se);

    if (lane < Cn) out[(size_t)b * Cn + lane] = mylogit - mx - lse;
}

// ---------------------------------------------------------------------------
extern "C" void kernel_launch(void* const* d_in, const int* in_sizes, int n_in,
                              void* d_out, int out_size, void* d_ws, size_t ws_size,
                              hipStream_t stream) {
    const int*   nodes     = (const int*)d_in[0];
    const int*   structure = (const int*)d_in[1];
    const float* X         = (const float*)d_in[2];
    const float* beta      = (const float*)d_in[3];
    const float* waw       = (const float*)d_in[4];
    const float* wab       = (const float*)d_in[5];
    const float* linW      = (const float*)d_in[6];
    const float* linb      = (const float*)d_in[7];
    const float* skipW     = (const float*)d_in[8];
    const float* clsW      = (const float*)d_in[9];
    const float* clsb      = (const float*)d_in[10];
    float* out = (float*)d_out;

    const int B = in_sizes[0];
    const int Ntot = in_sizes[2];            // N * D floats

    // ws layout (bf16 path):
    //   h_bf   [B,D]   bf16
    //   selfb  [B,D]   bf16
    //   Xb     [N,D]   bf16
    //   linWb  [H,D]   bf16
    //   skipWb [H,D]   bf16
    //   clsWb  [48,H]  bf16 (zero-padded)
    unsigned short* h_bf   = (unsigned short*)d_ws;
    unsigned short* selfb  = h_bf + (size_t)B * Dn;
    unsigned short* Xb     = selfb + (size_t)B * Dn;
    unsigned short* linWb  = Xb + (size_t)Ntot;
    unsigned short* skipWb = linWb + (size_t)Hn * Dn;
    unsigned short* clsWb  = skipWb + (size_t)Hn * Dn;

    const size_t need = ((size_t)B * Dn * 2 + (size_t)Ntot +
                         (size_t)Hn * Dn * 2 + (size_t)CnP * Hn) * 2;

    if (ws_size >= need) {
        // Stage 0: one merged bf16 conversion launch
        const int x8 = Ntot / 8;
        const int w8 = (Hn * Dn) / 8;
        const int c8 = (CnP * Hn) / 8;
        const int G = x8 + 2 * w8 + c8;
        conv_all<<<(G + 255) / 256, 256, 0, stream>>>(
            X, linW, skipW, clsW,
            (uint4*)Xb, (uint4*)linWb, (uint4*)skipWb, (uint4*)clsWb, x8, w8);

        // Stage 1: message passing (bf16 gathers) -> h_bf, selfb
        mp_kernel_bf<<<(B + 3) / 4, 256, 0, stream>>>(
            nodes, structure, (const uint2*)Xb, waw, wab,
            (uint2*)h_bf, (uint2*)selfb, B);

        // Stage 2+3: fused dual-GEMM + classifier + log_softmax -> out
        enc_cls_fused<<<(B + 31) / 32, 256, 0, stream>>>(
            h_bf, selfb, linWb, linb, skipWb, beta, clsWb, clsb, out, B);
    } else {
        float* enc2 = (float*)d_ws;
        float* hf   = enc2 + (size_t)B * Hn;
        mp_kernel_f32<<<(B + 3) / 4, 256, 0, stream>>>(nodes, structure, X, waw, wab, hf, B);
        dim3 g2((B + BM - 1) / BM, Hn / BN);
        enc_gemm_f32<<<g2, 256, 0, stream>>>(hf, nodes, X, linW, linb, skipW, beta, enc2, B);
        cls_kernel_f32<<<(B + 3) / 4, 256, 0, stream>>>(enc2, clsW, clsb, out, B);
    }
}

// Round 9
// 124.161 us; speedup vs baseline: 2.2675x; 1.1143x over previous
//
#include <hip/hip_runtime.h>
#include <hip/hip_bf16.h>
#include <math.h>

// Problem constants (from reference)
#define Dn 256     // feature dim
#define En 16      // hyperedges per node
#define Kn 3       // nodes per hyperedge
#define Hn 256     // hidden dim
#define Cn 40      // classes
#define CnP 48     // classes padded to 3x16 for MFMA col tiles

typedef __attribute__((ext_vector_type(8)))  short bf16x8;
typedef __attribute__((ext_vector_type(4)))  float f32x4;
typedef __attribute__((ext_vector_type(16))) float f32x16;

static __device__ __forceinline__ float bf2f(unsigned short u) {
    return __uint_as_float(((unsigned)u) << 16);
}
static __device__ __forceinline__ unsigned short f2bfbits(float v) {
    __hip_bfloat16 hb = __float2bfloat16(v);
    return *reinterpret_cast<unsigned short*>(&hb);
}
static __device__ __forceinline__ unsigned pack2bf(float a, float b) {
    return (unsigned)f2bfbits(a) | ((unsigned)f2bfbits(b) << 16);
}
// 5-bit LDS swizzle for 32x512B tiles: XOR row (bits 9..13) into the 16B-slot
// index (bits 4..8). Fixed slot-column + 32 distinct rows -> 32 distinct
// slots -> conflict-free ds_read_b128 across a 32-lane group.
static __device__ __forceinline__ unsigned swz5(unsigned boff) {
    return boff ^ (((boff >> 9) & 31u) << 4);
}

// ---------------------------------------------------------------------------
// Stage 0: merged fp32 -> bf16 conversion: X, lin_W, skip_W, cls_W (padded
// to 48 rows with zeros). One launch; each thread converts 8 floats.
// ---------------------------------------------------------------------------
__global__ __launch_bounds__(256) void conv_all(
    const float* __restrict__ X, const float* __restrict__ linW,
    const float* __restrict__ skipW, const float* __restrict__ clsW,
    uint4* __restrict__ Xb, uint4* __restrict__ linWb,
    uint4* __restrict__ skipWb, uint4* __restrict__ clsWb,
    int x8, int w8)
{
    int t = blockIdx.x * 256 + threadIdx.x;
    const int c8 = (CnP * Hn) / 8;
    if (t < x8) {
        const float4* iv = reinterpret_cast<const float4*>(X);
        const float4 a = iv[(size_t)t * 2 + 0];
        const float4 b = iv[(size_t)t * 2 + 1];
        Xb[t] = (uint4){pack2bf(a.x, a.y), pack2bf(a.z, a.w),
                        pack2bf(b.x, b.y), pack2bf(b.z, b.w)};
        return;
    }
    t -= x8;
    if (t < w8) {
        const float4* iv = reinterpret_cast<const float4*>(linW);
        const float4 a = iv[(size_t)t * 2 + 0];
        const float4 b = iv[(size_t)t * 2 + 1];
        linWb[t] = (uint4){pack2bf(a.x, a.y), pack2bf(a.z, a.w),
                           pack2bf(b.x, b.y), pack2bf(b.z, b.w)};
        return;
    }
    t -= w8;
    if (t < w8) {
        const float4* iv = reinterpret_cast<const float4*>(skipW);
        const float4 a = iv[(size_t)t * 2 + 0];
        const float4 b = iv[(size_t)t * 2 + 1];
        skipWb[t] = (uint4){pack2bf(a.x, a.y), pack2bf(a.z, a.w),
                            pack2bf(b.x, b.y), pack2bf(b.z, b.w)};
        return;
    }
    t -= w8;
    if (t < c8) {
        const int row = t >> 5;
        if (row < Cn) {
            const float4* iv = reinterpret_cast<const float4*>(clsW);
            const float4 a = iv[(size_t)t * 2 + 0];
            const float4 b = iv[(size_t)t * 2 + 1];
            clsWb[t] = (uint4){pack2bf(a.x, a.y), pack2bf(a.z, a.w),
                               pack2bf(b.x, b.y), pack2bf(b.z, b.w)};
        } else {
            clsWb[t] = (uint4){0u, 0u, 0u, 0u};
        }
    }
}

// ---------------------------------------------------------------------------
// MEGA-KERNEL: message passing -> LDS -> dual GEMM (32x32x16 MFMA) ->
// classifier (16x16x32) -> log_softmax -> out. Block = 32 nodes, 4 waves.
//
// mp phase: each wave processes 8 nodes serially (16 edges each, groups of 4,
// 12 gathers in flight). h and self rows land in swizzled LDS (2x16KB).
// GEMM phase: wave w owns cols [w*64,w*64+64) of all 32 rows; A-fragments
// from LDS (conflict-free via swz5), B from global (L2-hot weights).
// enc result overwrites hlds; waves 0,1 run cls from it.
// Desynchronized blocks overlap GEMM compute with other blocks' gathers.
// ---------------------------------------------------------------------------
__global__ __launch_bounds__(256, 4) void mp_enc_cls(
    const int* __restrict__ nodes, const int* __restrict__ structure,
    const uint2* __restrict__ Xb,
    const float* __restrict__ waw_p, const float* __restrict__ wab_p,
    const unsigned short* __restrict__ linWb, const float* __restrict__ linb,
    const unsigned short* __restrict__ skipWb, const float* __restrict__ beta_p,
    const unsigned short* __restrict__ clsWb, const float* __restrict__ clsb,
    float* __restrict__ out, int B)
{
    __shared__ unsigned short hlds[32 * 256];  // 16 KB (h; later enc)
    __shared__ unsigned short slds[32 * 256];  // 16 KB (self)

    const int wid  = threadIdx.x >> 6;
    const int lane = threadIdx.x & 63;
    const int row0 = blockIdx.x * 32;

    const float waw = waw_p[0];
    const float wab = wab_p[0];

    // ---------------- mp phase: 8 nodes per wave ----------------
    #pragma unroll 1
    for (int j = 0; j < 8; ++j) {
        const int rowl = wid * 8 + j;
        const int b = row0 + rowl;
        if (b < B) {
            const int ub = __builtin_amdgcn_readfirstlane(b);
            const int* st = structure + (size_t)ub * (En * Kn);

            float4 neigh = make_float4(0.f, 0.f, 0.f, 0.f);

            #pragma unroll 1
            for (int g = 0; g < En / 4; ++g) {
                int idx[12];
                #pragma unroll
                for (int u = 0; u < 12; ++u) idx[u] = st[g * 12 + u];

                uint2 r0[4], r1[4], r2[4];
                #pragma unroll
                for (int u = 0; u < 4; ++u) {
                    r0[u] = Xb[(size_t)idx[u * 3 + 0] * (Dn / 4) + lane];
                    r1[u] = Xb[(size_t)idx[u * 3 + 1] * (Dn / 4) + lane];
                    r2[u] = Xb[(size_t)idx[u * 3 + 2] * (Dn / 4) + lane];
                }

                float pv[4];
                float4 msg[4];
                #pragma unroll
                for (int u = 0; u < 4; ++u) {
                    float4 f0, f1, f2;
                    f0.x = bf2f((unsigned short)(r0[u].x & 0xffff));
                    f0.y = bf2f((unsigned short)(r0[u].x >> 16));
                    f0.z = bf2f((unsigned short)(r0[u].y & 0xffff));
                    f0.w = bf2f((unsigned short)(r0[u].y >> 16));
                    f1.x = bf2f((unsigned short)(r1[u].x & 0xffff));
                    f1.y = bf2f((unsigned short)(r1[u].x >> 16));
                    f1.z = bf2f((unsigned short)(r1[u].y & 0xffff));
                    f1.w = bf2f((unsigned short)(r1[u].y >> 16));
                    f2.x = bf2f((unsigned short)(r2[u].x & 0xffff));
                    f2.y = bf2f((unsigned short)(r2[u].x >> 16));
                    f2.z = bf2f((unsigned short)(r2[u].y & 0xffff));
                    f2.w = bf2f((unsigned short)(r2[u].y >> 16));

                    float s2 = 0.f, cr = 0.f, tt;
                    s2 = fmaf(f0.x, f0.x, s2); s2 = fmaf(f1.x, f1.x, s2); s2 = fmaf(f2.x, f2.x, s2);
                    tt = f1.x + f2.x; cr = fmaf(f0.x, tt, cr); cr = fmaf(f1.x, f2.x, cr);
                    s2 = fmaf(f0.y, f0.y, s2); s2 = fmaf(f1.y, f1.y, s2); s2 = fmaf(f2.y, f2.y, s2);
                    tt = f1.y + f2.y; cr = fmaf(f0.y, tt, cr); cr = fmaf(f1.y, f2.y, cr);
                    s2 = fmaf(f0.z, f0.z, s2); s2 = fmaf(f1.z, f1.z, s2); s2 = fmaf(f2.z, f2.z, s2);
                    tt = f1.z + f2.z; cr = fmaf(f0.z, tt, cr); cr = fmaf(f1.z, f2.z, cr);
                    s2 = fmaf(f0.w, f0.w, s2); s2 = fmaf(f1.w, f1.w, s2); s2 = fmaf(f2.w, f2.w, s2);
                    tt = f1.w + f2.w; cr = fmaf(f0.w, tt, cr); cr = fmaf(f1.w, f2.w, cr);

                    pv[u] = s2 - cr;
                    msg[u].x = f0.x * f1.x;
                    msg[u].y = f0.y * f1.y;
                    msg[u].z = f0.z * f1.z;
                    msg[u].w = f0.w * f1.w;
                }

                #pragma unroll
                for (int off = 32; off; off >>= 1) {
                    #pragma unroll
                    for (int u = 0; u < 4; ++u) pv[u] += __shfl_xor(pv[u], off);
                }

                #pragma unroll
                for (int u = 0; u < 4; ++u) {
                    const float var_mean = pv[u] * (2.f / (9.f * (float)Dn));
                    const float att = 1.f / (1.f + expf(-(waw * var_mean + wab)));
                    neigh.x += att * msg[u].x;
                    neigh.y += att * msg[u].y;
                    neigh.z += att * msg[u].z;
                    neigh.w += att * msg[u].w;
                }
            }

            const uint2 sv = Xb[(size_t)nodes[ub] * (Dn / 4) + lane];
            const float sx = bf2f((unsigned short)(sv.x & 0xffff));
            const float sy = bf2f((unsigned short)(sv.x >> 16));
            const float sz = bf2f((unsigned short)(sv.y & 0xffff));
            const float sw = bf2f((unsigned short)(sv.y >> 16));
            uint2 o;
            o.x = pack2bf(sx + neigh.x, sy + neigh.y);
            o.y = pack2bf(sz + neigh.z, sw + neigh.w);

            const unsigned boff = swz5((unsigned)(rowl * 512 + lane * 8));
            *reinterpret_cast<uint2*>(reinterpret_cast<char*>(slds) + boff) = sv;
            *reinterpret_cast<uint2*>(reinterpret_cast<char*>(hlds) + boff) = o;
        }
    }
    __syncthreads();

    // ---------------- GEMM phase: wave wid owns cols [wid*64, +64) ----------
    const int lr = lane & 31;
    const int kh = lane >> 5;
    const int bc0 = wid * 64 + lr;
    const int bc1 = wid * 64 + 32 + lr;

    f32x16 acc1[2], acc2[2];
    acc1[0] = (f32x16)(0.f); acc1[1] = (f32x16)(0.f);
    acc2[0] = (f32x16)(0.f); acc2[1] = (f32x16)(0.f);

    #pragma unroll 2
    for (int k0 = 0; k0 < Dn; k0 += 16) {
        const int ko = k0 + kh * 8;
        const unsigned aoff = swz5((unsigned)(lr * 512 + ko * 2));
        const bf16x8 a1 = *reinterpret_cast<const bf16x8*>(
            reinterpret_cast<const char*>(hlds) + aoff);
        const bf16x8 a2 = *reinterpret_cast<const bf16x8*>(
            reinterpret_cast<const char*>(slds) + aoff);
        const bf16x8 b10 = *reinterpret_cast<const bf16x8*>(linWb  + (size_t)bc0 * Dn + ko);
        const bf16x8 b11 = *reinterpret_cast<const bf16x8*>(linWb  + (size_t)bc1 * Dn + ko);
        const bf16x8 b20 = *reinterpret_cast<const bf16x8*>(skipWb + (size_t)bc0 * Dn + ko);
        const bf16x8 b21 = *reinterpret_cast<const bf16x8*>(skipWb + (size_t)bc1 * Dn + ko);
        acc1[0] = __builtin_amdgcn_mfma_f32_32x32x16_bf16(a1, b10, acc1[0], 0, 0, 0);
        acc1[1] = __builtin_amdgcn_mfma_f32_32x32x16_bf16(a1, b11, acc1[1], 0, 0, 0);
        acc2[0] = __builtin_amdgcn_mfma_f32_32x32x16_bf16(a2, b20, acc2[0], 0, 0, 0);
        acc2[1] = __builtin_amdgcn_mfma_f32_32x32x16_bf16(a2, b21, acc2[1], 0, 0, 0);
    }
    __syncthreads();   // all waves done reading hlds before enc overwrites it

    // epilogue: enc -> hlds (swizzled bf16)
    const float beta = beta_p[0];
    const float omb = 1.f - beta;
    #pragma unroll
    for (int n = 0; n < 2; ++n) {
        const int col = wid * 64 + n * 32 + lr;
        const float bias = linb[col];
        #pragma unroll
        for (int r = 0; r < 16; ++r) {
            const int rowl = (r & 3) + 8 * (r >> 2) + 4 * kh;   // 0..31
            const float c1 = fmaxf(acc1[n][r] + bias, 0.f);
            const unsigned short v = f2bfbits(omb * c1 + beta * acc2[n][r]);
            const unsigned boff = swz5((unsigned)(rowl * 512 + col * 2));
            *reinterpret_cast<unsigned short*>(
                reinterpret_cast<char*>(hlds) + boff) = v;
        }
    }
    __syncthreads();

    // ---------------- cls phase: waves 0,1 each handle 16 rows --------------
    if (wid < 2) {
        const int lr16 = lane & 15;
        const int kg = lane >> 4;
        const int rowl0 = wid * 16 + lr16;

        f32x4 cacc[3];
        cacc[0] = (f32x4){0.f,0.f,0.f,0.f};
        cacc[1] = (f32x4){0.f,0.f,0.f,0.f};
        cacc[2] = (f32x4){0.f,0.f,0.f,0.f};

        #pragma unroll
        for (int k0 = 0; k0 < Hn; k0 += 32) {
            const int ko = k0 + kg * 8;
            const unsigned boff = swz5((unsigned)(rowl0 * 512 + ko * 2));
            const bf16x8 a = *reinterpret_cast<const bf16x8*>(
                reinterpret_cast<const char*>(hlds) + boff);
            #pragma unroll
            for (int t = 0; t < 3; ++t) {
                const bf16x8 bb = *reinterpret_cast<const bf16x8*>(
                    clsWb + (size_t)(t * 16 + lr16) * Hn + ko);
                cacc[t] = __builtin_amdgcn_mfma_f32_16x16x32_bf16(a, bb, cacc[t], 0, 0, 0);
            }
        }

        float bias3[3];
        #pragma unroll
        for (int t = 0; t < 3; ++t) {
            const int cb = t * 16 + lr16;
            bias3[t] = (cb < Cn) ? clsb[cb] : -INFINITY;
        }

        #pragma unroll
        for (int r = 0; r < 4; ++r) {
            float lg0 = cacc[0][r] + bias3[0];
            float lg1 = cacc[1][r] + bias3[1];
            float lg2 = cacc[2][r] + bias3[2];
            float mx = fmaxf(fmaxf(lg0, lg1), lg2);
            #pragma unroll
            for (int off = 8; off; off >>= 1) mx = fmaxf(mx, __shfl_xor(mx, off));
            float se = expf(lg0 - mx) + expf(lg1 - mx) + expf(lg2 - mx);
            #pragma unroll
            for (int off = 8; off; off >>= 1) se += __shfl_xor(se, off);
            const float lse = logf(se);

            const int row = row0 + wid * 16 + kg * 4 + r;
            if (row < B) {
                if (lr16 < 8) out[(size_t)row * Cn + 32 + lr16] = lg2 - mx - lse;
                out[(size_t)row * Cn + lr16]      = lg0 - mx - lse;
                out[(size_t)row * Cn + 16 + lr16] = lg1 - mx - lse;
            }
        }
    }
}

// ---------------------------------------------------------------------------
// fp32 fallback path (only if ws_size too small for bf16 copies)
// ---------------------------------------------------------------------------
__global__ __launch_bounds__(256) void mp_kernel_f32(
    const int* __restrict__ nodes, const int* __restrict__ structure,
    const float* __restrict__ X, const float* __restrict__ waw_p,
    const float* __restrict__ wab_p, float* __restrict__ h_out, int B)
{
    const int wave = threadIdx.x >> 6;
    const int lane = threadIdx.x & 63;
    const int b = blockIdx.x * 4 + wave;
    if (b >= B) return;
    const int ub = __builtin_amdgcn_readfirstlane(b);

    const float waw = waw_p[0];
    const float wab = wab_p[0];
    const float4* __restrict__ Xv = reinterpret_cast<const float4*>(X);

    float4 neigh = make_float4(0.f, 0.f, 0.f, 0.f);
    const int* st = structure + (size_t)ub * (En * Kn);

    #pragma unroll 1
    for (int e = 0; e < En; ++e) {
        const int i0 = st[e * 3 + 0];
        const int i1 = st[e * 3 + 1];
        const int i2 = st[e * 3 + 2];
        const float4 f0 = Xv[(size_t)i0 * (Dn / 4) + lane];
        const float4 f1 = Xv[(size_t)i1 * (Dn / 4) + lane];
        const float4 f2 = Xv[(size_t)i2 * (Dn / 4) + lane];
        float pv = 0.f;
        {
            float a, bb, c, m;
            a = f0.x; bb = f1.x; c = f2.x;
            m = (a + bb + c) * (1.f / 3.f);
            pv += (a * a + bb * bb + c * c) * (1.f / 3.f) - m * m;
            a = f0.y; bb = f1.y; c = f2.y;
            m = (a + bb + c) * (1.f / 3.f);
            pv += (a * a + bb * bb + c * c) * (1.f / 3.f) - m * m;
            a = f0.z; bb = f1.z; c = f2.z;
            m = (a + bb + c) * (1.f / 3.f);
            pv += (a * a + bb * bb + c * c) * (1.f / 3.f) - m * m;
            a = f0.w; bb = f1.w; c = f2.w;
            m = (a + bb + c) * (1.f / 3.f);
            pv += (a * a + bb * bb + c * c) * (1.f / 3.f) - m * m;
        }
        #pragma unroll
        for (int off = 32; off; off >>= 1) pv += __shfl_xor(pv, off);
        const float var_mean = pv * (1.f / (float)Dn);
        const float att = 1.f / (1.f + expf(-(waw * var_mean + wab)));
        neigh.x += att * f0.x * f1.x;
        neigh.y += att * f0.y * f1.y;
        neigh.z += att * f0.z * f1.z;
        neigh.w += att * f0.w * f1.w;
    }

    const float4 s = Xv[(size_t)nodes[ub] * (Dn / 4) + lane];
    float4 h;
    h.x = s.x + neigh.x; h.y = s.y + neigh.y;
    h.z = s.z + neigh.z; h.w = s.w + neigh.w;
    reinterpret_cast<float4*>(h_out)[(size_t)b * (Dn / 4) + lane] = h;
}

#define BM 64
#define BN 64
#define BKs 16
#define LDT 68

__global__ __launch_bounds__(256) void enc_gemm_f32(
    const float* __restrict__ hA, const int* __restrict__ nodes,
    const float* __restrict__ X,
    const float* __restrict__ linW, const float* __restrict__ linb,
    const float* __restrict__ skipW, const float* __restrict__ beta_p,
    float* __restrict__ enc2, int M)
{
    __shared__ float Ats1[BKs][LDT];
    __shared__ float Ats2[BKs][LDT];
    __shared__ float Bts1[BKs][LDT];
    __shared__ float Bts2[BKs][LDT];

    const int tid = threadIdx.x;
    const int tx = tid & 15;
    const int ty = tid >> 4;
    const int row0 = blockIdx.x * BM;
    const int col0 = blockIdx.y * BN;

    const int lr = tid >> 2;
    const int lc = tid & 3;

    const int arow = row0 + lr;
    const bool arow_ok = arow < M;
    const int self_row = arow_ok ? nodes[arow] : 0;

    float acc1[4][4] = {{0.f}}, acc2[4][4] = {{0.f}};

    for (int k0 = 0; k0 < Dn; k0 += BKs) {
        float4 a1v = make_float4(0.f, 0.f, 0.f, 0.f);
        float4 a2v = make_float4(0.f, 0.f, 0.f, 0.f);
        if (arow_ok) {
            a1v = *reinterpret_cast<const float4*>(hA + (size_t)arow * Dn + k0 + lc * 4);
            a2v = *reinterpret_cast<const float4*>(X + (size_t)self_row * Dn + k0 + lc * 4);
        }
        const float4 b1v = *reinterpret_cast<const float4*>(linW + (size_t)(col0 + lr) * Dn + k0 + lc * 4);
        const float4 b2v = *reinterpret_cast<const float4*>(skipW + (size_t)(col0 + lr) * Dn + k0 + lc * 4);

        __syncthreads();
        Ats1[lc * 4 + 0][lr] = a1v.x; Ats1[lc * 4 + 1][lr] = a1v.y;
        Ats1[lc * 4 + 2][lr] = a1v.z; Ats1[lc * 4 + 3][lr] = a1v.w;
        Ats2[lc * 4 + 0][lr] = a2v.x; Ats2[lc * 4 + 1][lr] = a2v.y;
        Ats2[lc * 4 + 2][lr] = a2v.z; Ats2[lc * 4 + 3][lr] = a2v.w;
        Bts1[lc * 4 + 0][lr] = b1v.x; Bts1[lc * 4 + 1][lr] = b1v.y;
        Bts1[lc * 4 + 2][lr] = b1v.z; Bts1[lc * 4 + 3][lr] = b1v.w;
        Bts2[lc * 4 + 0][lr] = b2v.x; Bts2[lc * 4 + 1][lr] = b2v.y;
        Bts2[lc * 4 + 2][lr] = b2v.z; Bts2[lc * 4 + 3][lr] = b2v.w;
        __syncthreads();

        #pragma unroll
        for (int kk = 0; kk < BKs; ++kk) {
            const float4 a1 = *reinterpret_cast<const float4*>(&Ats1[kk][ty * 4]);
            const float4 a2 = *reinterpret_cast<const float4*>(&Ats2[kk][ty * 4]);
            const float4 b1 = *reinterpret_cast<const float4*>(&Bts1[kk][tx * 4]);
            const float4 b2 = *reinterpret_cast<const float4*>(&Bts2[kk][tx * 4]);
            const float a1a[4] = {a1.x, a1.y, a1.z, a1.w};
            const float a2a[4] = {a2.x, a2.y, a2.z, a2.w};
            const float b1a[4] = {b1.x, b1.y, b1.z, b1.w};
            const float b2a[4] = {b2.x, b2.y, b2.z, b2.w};
            #pragma unroll
            for (int i = 0; i < 4; ++i)
                #pragma unroll
                for (int j = 0; j < 4; ++j) {
                    acc1[i][j] = fmaf(a1a[i], b1a[j], acc1[i][j]);
                    acc2[i][j] = fmaf(a2a[i], b2a[j], acc2[i][j]);
                }
        }
    }

    const float beta = beta_p[0];
    const float omb = 1.f - beta;
    #pragma unroll
    for (int i = 0; i < 4; ++i) {
        const int r = row0 + ty * 4 + i;
        if (r >= M) continue;
        #pragma unroll
        for (int j = 0; j < 4; ++j) {
            const int c = col0 + tx * 4 + j;
            float c1 = acc1[i][j] + linb[c];
            c1 = fmaxf(c1, 0.f);
            enc2[(size_t)r * Hn + c] = omb * c1 + beta * acc2[i][j];
        }
    }
}

__global__ __launch_bounds__(256) void cls_kernel_f32(
    const float* __restrict__ enc2, const float* __restrict__ clsW,
    const float* __restrict__ clsb, float* __restrict__ out, int B)
{
    const int wave = threadIdx.x >> 6;
    const int lane = threadIdx.x & 63;
    const int b = blockIdx.x * 4 + wave;
    if (b >= B) return;

    const float4 e = reinterpret_cast<const float4*>(enc2 + (size_t)b * Hn)[lane];
    const float4* __restrict__ clsWv = reinterpret_cast<const float4*>(clsW);

    float mylogit = -INFINITY;
    #pragma unroll
    for (int c0 = 0; c0 < Cn; c0 += 8) {
        float p[8];
        #pragma unroll
        for (int u = 0; u < 8; ++u) {
            const float4 wv = clsWv[(size_t)(c0 + u) * (Hn / 4) + lane];
            p[u] = e.x * wv.x + e.y * wv.y + e.z * wv.z + e.w * wv.w;
        }
        #pragma unroll
        for (int off = 32; off; off >>= 1) {
            #pragma unroll
            for (int u = 0; u < 8; ++u) p[u] += __shfl_xor(p[u], off);
        }
        #pragma unroll
        for (int u = 0; u < 8; ++u)
            if (lane == c0 + u) mylogit = p[u];
    }
    if (lane < Cn) mylogit += clsb[lane];

    float mx = mylogit;
    #pragma unroll
    for (int off = 32; off; off >>= 1) mx = fmaxf(mx, __shfl_xor(mx, off));
    float ex = (lane < Cn) ? expf(mylogit - mx) : 0.f;
    float se = ex;
    #pragma unroll
    for (int off = 32; off; off >>= 1) se += __shfl_xor(se, off);
    const float lse = logf(se);

    if (lane < Cn) out[(size_t)b * Cn + lane] = mylogit - mx - lse;
}

// ---------------------------------------------------------------------------
extern "C" void kernel_launch(void* const* d_in, const int* in_sizes, int n_in,
                              void* d_out, int out_size, void* d_ws, size_t ws_size,
                              hipStream_t stream) {
    const int*   nodes     = (const int*)d_in[0];
    const int*   structure = (const int*)d_in[1];
    const float* X         = (const float*)d_in[2];
    const float* beta      = (const float*)d_in[3];
    const float* waw       = (const float*)d_in[4];
    const float* wab       = (const float*)d_in[5];
    const float* linW      = (const float*)d_in[6];
    const float* linb      = (const float*)d_in[7];
    const float* skipW     = (const float*)d_in[8];
    const float* clsW      = (const float*)d_in[9];
    const float* clsb      = (const float*)d_in[10];
    float* out = (float*)d_out;

    const int B = in_sizes[0];
    const int Ntot = in_sizes[2];            // N * D floats

    // ws layout (bf16 path):
    //   Xb     [N,D]   bf16
    //   linWb  [H,D]   bf16
    //   skipWb [H,D]   bf16
    //   clsWb  [48,H]  bf16 (zero-padded)
    unsigned short* Xb     = (unsigned short*)d_ws;
    unsigned short* linWb  = Xb + (size_t)Ntot;
    unsigned short* skipWb = linWb + (size_t)Hn * Dn;
    unsigned short* clsWb  = skipWb + (size_t)Hn * Dn;

    const size_t need = ((size_t)Ntot + (size_t)Hn * Dn * 2 + (size_t)CnP * Hn) * 2;

    if (ws_size >= need) {
        // Stage 0: one merged bf16 conversion launch
        const int x8 = Ntot / 8;
        const int w8 = (Hn * Dn) / 8;
        const int c8 = (CnP * Hn) / 8;
        const int G = x8 + 2 * w8 + c8;
        conv_all<<<(G + 255) / 256, 256, 0, stream>>>(
            X, linW, skipW, clsW,
            (uint4*)Xb, (uint4*)linWb, (uint4*)skipWb, (uint4*)clsWb, x8, w8);

        // Mega-kernel: mp -> LDS -> dual GEMM -> cls -> out
        mp_enc_cls<<<(B + 31) / 32, 256, 0, stream>>>(
            nodes, structure, (const uint2*)Xb, waw, wab,
            linWb, linb, skipWb, beta, clsWb, clsb, out, B);
    } else {
        float* enc2 = (float*)d_ws;
        float* hf   = enc2 + (size_t)B * Hn;
        mp_kernel_f32<<<(B + 3) / 4, 256, 0, stream>>>(nodes, structure, X, waw, wab, hf, B);
        dim3 g2((B + BM - 1) / BM, Hn / BN);
        enc_gemm_f32<<<g2, 256, 0, stream>>>(hf, nodes, X, linW, linb, skipW, beta, enc2, B);
        cls_kernel_f32<<<(B + 3) / 4, 256, 0, stream>>>(enc2, clsW, clsb, out, B);
    }
}